// Round 6
// baseline (6039.299 us; speedup 1.0000x reference)
//
#include <hip/hip_runtime.h>
#include <hip/hip_bf16.h>

#define TT 512
#define DD 256
#define NH 4
#define NN 4096
#define VV 256
#define NLAYER 6
#define NPAIR 2048  // NN/2

// ---------------- block-wide sum over 256 threads ----------------
__device__ __forceinline__ float block_sum_256(float v) {
  __shared__ float s[4];
  #pragma unroll
  for (int o = 32; o > 0; o >>= 1) v += __shfl_down(v, o);
  int lane = threadIdx.x & 63, wid = threadIdx.x >> 6;
  if (lane == 0) s[wid] = v;
  __syncthreads();
  float r = s[0] + s[1] + s[2] + s[3];
  __syncthreads();
  return r;
}

// ---------------- 64x64 f32 tile GEMM: C(64x64) += A(64xK) * B(Kx64) ----------------
__device__ __forceinline__ void gemm64(const float* __restrict__ A, int lda,
                                       const float* __restrict__ B, int ldb,
                                       int K, float acc[4][4]) {
  __shared__ float As[16][65];
  __shared__ float Bs[16][64];
  const int tid = threadIdx.x;
  const int tx = tid & 15, ty = tid >> 4;
  const int am = tid >> 2, ak = (tid & 3) << 2;
  const int bk = tid >> 4, bn = (tid & 15) << 2;
  for (int k0 = 0; k0 < K; k0 += 16) {
    float4 av = *(const float4*)(A + am * lda + k0 + ak);
    float4 bv = *(const float4*)(B + (k0 + bk) * ldb + bn);
    As[ak + 0][am] = av.x; As[ak + 1][am] = av.y;
    As[ak + 2][am] = av.z; As[ak + 3][am] = av.w;
    *(float4*)(&Bs[bk][bn]) = bv;
    __syncthreads();
    #pragma unroll
    for (int k = 0; k < 16; ++k) {
      float a0 = As[k][(ty << 2) + 0], a1 = As[k][(ty << 2) + 1];
      float a2 = As[k][(ty << 2) + 2], a3 = As[k][(ty << 2) + 3];
      float4 b4 = *(const float4*)(&Bs[k][tx << 2]);
      acc[0][0] = fmaf(a0, b4.x, acc[0][0]); acc[0][1] = fmaf(a0, b4.y, acc[0][1]);
      acc[0][2] = fmaf(a0, b4.z, acc[0][2]); acc[0][3] = fmaf(a0, b4.w, acc[0][3]);
      acc[1][0] = fmaf(a1, b4.x, acc[1][0]); acc[1][1] = fmaf(a1, b4.y, acc[1][1]);
      acc[1][2] = fmaf(a1, b4.z, acc[1][2]); acc[1][3] = fmaf(a1, b4.w, acc[1][3]);
      acc[2][0] = fmaf(a2, b4.x, acc[2][0]); acc[2][1] = fmaf(a2, b4.y, acc[2][1]);
      acc[2][2] = fmaf(a2, b4.z, acc[2][2]); acc[2][3] = fmaf(a2, b4.w, acc[2][3]);
      acc[3][0] = fmaf(a3, b4.x, acc[3][0]); acc[3][1] = fmaf(a3, b4.y, acc[3][1]);
      acc[3][2] = fmaf(a3, b4.z, acc[3][2]); acc[3][3] = fmaf(a3, b4.w, acc[3][3]);
    }
    __syncthreads();
  }
}

// ---------------- kernels ----------------

// cos/sin table: cs[t*NPAIR + p] = (cos(ph), sin(ph)), ph = frac(t*freq(2p))*2pi
__global__ __launch_bounds__(256) void k_csinit(float2* __restrict__ cs) {
  int idx = blockIdx.x * 256 + threadIdx.x;
  int t = idx >> 11, p = idx & (NPAIR - 1);
  const float INV2PI = 0.15915494309189535f;
  const float TWOPI = 6.283185307179586f;
  float f = exp2f(-16.0f * (float)(2 * p) / (float)NN) * INV2PI;
  float ph = fmodf((float)t * f, 1.0f) * TWOPI;
  float s, c;
  sincosf(ph, &s, &c);
  cs[idx] = make_float2(c, s);
}

// x[b,t,:] = LN(embed_table[ids[b,t], :]) — ids may be int64 or int32 words
__global__ __launch_bounds__(256) void k_embed_ln(const int* __restrict__ idw,
                                                  const float* __restrict__ tbl,
                                                  float* __restrict__ x) {
  __shared__ int s_id;
  int row = blockIdx.x, tid = threadIdx.x;
  if (tid == 0) {
    bool is64 = true;
    for (int i = 1; i < 64; i += 2)
      if (idw[i] != 0) { is64 = false; break; }
    s_id = is64 ? idw[2 * row] : idw[row];
  }
  __syncthreads();
  int id = s_id;
  float v = tbl[(size_t)id * DD + tid];
  float mu = block_sum_256(v) * (1.0f / DD);
  float d = v - mu;
  float var = block_sum_256(d * d) * (1.0f / DD);
  x[(size_t)row * DD + tid] = d * rsqrtf(var + 1e-5f);
}

// xsp = relu(x @ enc[h])
__global__ __launch_bounds__(256) void k_enc(const float* __restrict__ x,
                                             const float* __restrict__ enc,
                                             float* __restrict__ xsp) {
  const int bh = blockIdx.z, b = bh >> 2, h = bh & 3;
  const int m0 = blockIdx.y * 64, n0 = blockIdx.x * 64;
  float acc[4][4] = {};
  gemm64(x + (size_t)b * TT * DD + (size_t)m0 * DD, DD,
         enc + (size_t)h * DD * NN + n0, NN, DD, acc);
  const int tx = threadIdx.x & 15, ty = threadIdx.x >> 4;
  const size_t base = (size_t)bh * TT * NN;
  #pragma unroll
  for (int i = 0; i < 4; ++i) {
    int t = m0 + (ty << 2) + i;
    float4 sv;
    sv.x = fmaxf(acc[i][0], 0.0f); sv.y = fmaxf(acc[i][1], 0.0f);
    sv.z = fmaxf(acc[i][2], 0.0f); sv.w = fmaxf(acc[i][3], 0.0f);
    *(float4*)(xsp + base + (size_t)t * NN + n0 + (tx << 2)) = sv;
  }
}

// scores[t,s] = (s < t) ? rope(xsp[t,:]) · rope(xsp[s,:]) : 0   (rope on the fly)
__global__ __launch_bounds__(256) void k_scores(const float* __restrict__ xsp,
                                                const float2* __restrict__ cs,
                                                float* __restrict__ sc) {
  const int bh = blockIdx.z;
  const int m0 = blockIdx.y * 64, n0 = blockIdx.x * 64;
  const int tid = threadIdx.x, tx = tid & 15, ty = tid >> 4;
  float acc[4][4] = {};
  if (n0 < m0 + 64) {
    __shared__ float As[16][65];
    __shared__ float Bs[16][65];
    const float* Q = xsp + (size_t)bh * TT * NN;
    const int am = tid >> 2, ak = (tid & 3) << 2;
    const int ta = m0 + am, sb = n0 + am;
    for (int k0 = 0; k0 < NN; k0 += 16) {
      const int k = k0 + ak;
      float4 va = *(const float4*)(Q + (size_t)ta * NN + k);
      float4 ca = *(const float4*)((const float*)(cs + (size_t)ta * NPAIR + (k >> 1)));
      float4 vb = *(const float4*)(Q + (size_t)sb * NN + k);
      float4 cb = *(const float4*)((const float*)(cs + (size_t)sb * NPAIR + (k >> 1)));
      As[ak + 0][am] = va.x * ca.x - va.y * ca.y;
      As[ak + 1][am] = va.y * ca.x + va.x * ca.y;
      As[ak + 2][am] = va.z * ca.z - va.w * ca.w;
      As[ak + 3][am] = va.w * ca.z + va.z * ca.w;
      Bs[ak + 0][am] = vb.x * cb.x - vb.y * cb.y;
      Bs[ak + 1][am] = vb.y * cb.x + vb.x * cb.y;
      Bs[ak + 2][am] = vb.z * cb.z - vb.w * cb.w;
      Bs[ak + 3][am] = vb.w * cb.z + vb.z * cb.w;
      __syncthreads();
      #pragma unroll
      for (int kk = 0; kk < 16; ++kk) {
        float a0 = As[kk][(ty << 2) + 0], a1 = As[kk][(ty << 2) + 1];
        float a2 = As[kk][(ty << 2) + 2], a3 = As[kk][(ty << 2) + 3];
        float b0 = Bs[kk][(tx << 2) + 0], b1 = Bs[kk][(tx << 2) + 1];
        float b2 = Bs[kk][(tx << 2) + 2], b3 = Bs[kk][(tx << 2) + 3];
        acc[0][0] = fmaf(a0, b0, acc[0][0]); acc[0][1] = fmaf(a0, b1, acc[0][1]);
        acc[0][2] = fmaf(a0, b2, acc[0][2]); acc[0][3] = fmaf(a0, b3, acc[0][3]);
        acc[1][0] = fmaf(a1, b0, acc[1][0]); acc[1][1] = fmaf(a1, b1, acc[1][1]);
        acc[1][2] = fmaf(a1, b2, acc[1][2]); acc[1][3] = fmaf(a1, b3, acc[1][3]);
        acc[2][0] = fmaf(a2, b0, acc[2][0]); acc[2][1] = fmaf(a2, b1, acc[2][1]);
        acc[2][2] = fmaf(a2, b2, acc[2][2]); acc[2][3] = fmaf(a2, b3, acc[2][3]);
        acc[3][0] = fmaf(a3, b0, acc[3][0]); acc[3][1] = fmaf(a3, b1, acc[3][1]);
        acc[3][2] = fmaf(a3, b2, acc[3][2]); acc[3][3] = fmaf(a3, b3, acc[3][3]);
      }
      __syncthreads();
    }
  }
  float* C = sc + (size_t)bh * TT * TT;
  #pragma unroll
  for (int i = 0; i < 4; ++i) {
    int t = m0 + (ty << 2) + i;
    #pragma unroll
    for (int j = 0; j < 4; ++j) {
      int s = n0 + (tx << 2) + j;
      C[(size_t)t * TT + s] = (s < t) ? acc[i][j] : 0.0f;
    }
  }
}

// ykv = scores @ x   (pre-LN)
__global__ __launch_bounds__(256) void k_ykv(const float* __restrict__ sc,
                                             const float* __restrict__ x,
                                             float* __restrict__ ykv) {
  const int bh = blockIdx.z, b = bh >> 2;
  const int m0 = blockIdx.y * 64, n0 = blockIdx.x * 64;
  float acc[4][4] = {};
  gemm64(sc + (size_t)bh * TT * TT + (size_t)m0 * TT, TT,
         x + (size_t)b * TT * DD + n0, DD, TT, acc);
  const int tx = threadIdx.x & 15, ty = threadIdx.x >> 4;
  float* C = ykv + (size_t)bh * TT * DD;
  #pragma unroll
  for (int i = 0; i < 4; ++i) {
    float4 v = {acc[i][0], acc[i][1], acc[i][2], acc[i][3]};
    *(float4*)(C + (size_t)(m0 + (ty << 2) + i) * DD + n0 + (tx << 2)) = v;
  }
}

// in-place LN over rows of width 256
__global__ __launch_bounds__(256) void k_ln_rows(float* __restrict__ p) {
  int row = blockIdx.x, tid = threadIdx.x;
  float v = p[(size_t)row * DD + tid];
  float mu = block_sum_256(v) * (1.0f / DD);
  float d = v - mu;
  float var = block_sum_256(d * d) * (1.0f / DD);
  p[(size_t)row * DD + tid] = d * rsqrtf(var + 1e-5f);
}

// xsp = xsp * relu(ykv @ encv[h])   (in-place: xy overwrites x_sparse)
__global__ __launch_bounds__(256) void k_ysp_xy(const float* __restrict__ ykv,
                                                const float* __restrict__ encv,
                                                float* __restrict__ xsp) {
  const int bh = blockIdx.z, h = bh & 3;
  const int m0 = blockIdx.y * 64, n0 = blockIdx.x * 64;
  float acc[4][4] = {};
  gemm64(ykv + (size_t)bh * TT * DD + (size_t)m0 * DD, DD,
         encv + (size_t)h * DD * NN + n0, NN, DD, acc);
  const int tx = threadIdx.x & 15, ty = threadIdx.x >> 4;
  const size_t base = (size_t)bh * TT * NN;
  #pragma unroll
  for (int i = 0; i < 4; ++i) {
    int t = m0 + (ty << 2) + i;
    size_t off = base + (size_t)t * NN + n0 + (tx << 2);
    float4 xv = *(const float4*)(xsp + off);
    float4 o;
    o.x = xv.x * fmaxf(acc[i][0], 0.0f);
    o.y = xv.y * fmaxf(acc[i][1], 0.0f);
    o.z = xv.z * fmaxf(acc[i][2], 0.0f);
    o.w = xv.w * fmaxf(acc[i][3], 0.0f);
    *(float4*)(xsp + off) = o;
  }
}

// ym4[b,h] = xy[b,h] @ dec[h]   (per-head partials, summed in k_ln2)
__global__ __launch_bounds__(256) void k_ymlp(const float* __restrict__ xy,
                                              const float* __restrict__ dec,
                                              float* __restrict__ ym4) {
  const int bh = blockIdx.z, h = bh & 3;
  const int m0 = blockIdx.y * 64, n0 = blockIdx.x * 64;
  float acc[4][4] = {};
  gemm64(xy + (size_t)bh * TT * NN + (size_t)m0 * NN, NN,
         dec + (size_t)h * NN * DD + n0, DD, NN, acc);
  const int tx = threadIdx.x & 15, ty = threadIdx.x >> 4;
  float* C = ym4 + (size_t)bh * TT * DD;
  #pragma unroll
  for (int i = 0; i < 4; ++i) {
    float4 v = {acc[i][0], acc[i][1], acc[i][2], acc[i][3]};
    *(float4*)(C + (size_t)(m0 + (ty << 2) + i) * DD + n0 + (tx << 2)) = v;
  }
}

// x = LN(x + LN(sum_h ym4))
__global__ __launch_bounds__(256) void k_ln2(float* __restrict__ x,
                                             const float* __restrict__ ym4) {
  int row = blockIdx.x, tid = threadIdx.x;
  int b = row >> 9, t = row & 511;
  float y = 0.0f;
  #pragma unroll
  for (int h = 0; h < 4; ++h)
    y += ym4[(size_t)((b * 4 + h) * TT + t) * DD + tid];
  float mu = block_sum_256(y) * (1.0f / DD);
  float d = y - mu;
  float var = block_sum_256(d * d) * (1.0f / DD);
  float ly = d * rsqrtf(var + 1e-5f);
  float xv = x[(size_t)row * DD + tid] + ly;
  float mu2 = block_sum_256(xv) * (1.0f / DD);
  float d2 = xv - mu2;
  float var2 = block_sum_256(d2 * d2) * (1.0f / DD);
  x[(size_t)row * DD + tid] = d2 * rsqrtf(var2 + 1e-5f);
}

// neuron_trace[b, h*N+n] = mean_t xy[b,h,t,n]   (f32 output)
__global__ __launch_bounds__(256) void k_trace(const float* __restrict__ xy,
                                               float* __restrict__ out) {
  int idx = blockIdx.x * 256 + threadIdx.x;
  int b = idx >> 14, c = idx & 16383;
  int h = c >> 12, n = c & 4095;
  size_t base = (size_t)(b * 4 + h) * TT * NN + n;
  float s = 0.0f;
  for (int t = 0; t < TT; ++t) s += xy[base + (size_t)t * NN];
  out[idx] = s * (1.0f / TT);
}

// logits[b,t,:] = x[b,t,:] @ lm_head   (f32 output)
__global__ __launch_bounds__(256) void k_logits(const float* __restrict__ x,
                                                const float* __restrict__ W,
                                                float* __restrict__ out) {
  __shared__ float xs[DD];
  int row = blockIdx.x, tid = threadIdx.x;
  xs[tid] = x[(size_t)row * DD + tid];
  __syncthreads();
  float s = 0.0f;
  #pragma unroll 8
  for (int d = 0; d < DD; ++d) s = fmaf(xs[d], W[(size_t)d * VV + tid], s);
  out[(size_t)row * VV + tid] = s;
}

// embedding[b,d] = mean_t x[b,t,d]   (f32 output)
__global__ __launch_bounds__(256) void k_embedding(const float* __restrict__ x,
                                                   float* __restrict__ out) {
  int idx = blockIdx.x * 256 + threadIdx.x;
  int b = idx >> 8, d = idx & 255;
  float s = 0.0f;
  for (int t = 0; t < TT; ++t) s += x[(size_t)(b * TT + t) * DD + d];
  out[idx] = s * (1.0f / TT);
}

extern "C" void kernel_launch(void* const* d_in, const int* in_sizes, int n_in,
                              void* d_out, int out_size, void* d_ws, size_t ws_size,
                              hipStream_t stream) {
  const int*   ids  = (const int*)d_in[0];
  const float* tbl  = (const float*)d_in[1];
  const float* enc  = (const float*)d_in[2];
  const float* encv = (const float*)d_in[3];
  const float* dec  = (const float*)d_in[4];
  const float* lmh  = (const float*)d_in[5];
  const int B = 2;

  // workspace: 89 MiB
  float*  ws  = (float*)d_ws;
  float*  x   = ws;                                  //   262,144 f
  float*  xsp = x   + (size_t)B * TT * DD;           // 16,777,216 f (x_sparse, then xy in-place)
  float*  sc  = xsp + (size_t)B * NH * TT * NN;      //  2,097,152 f
  float*  ykv = sc  + (size_t)B * NH * TT * TT;      //  1,048,576 f
  float*  ym4 = ykv + (size_t)B * NH * TT * DD;      //  1,048,576 f
  float2* cs  = (float2*)(ym4 + (size_t)B * NH * TT * DD);  // 1,048,576 float2 = 8 MiB

  // OUTPUTS ARE FLOAT32 (reference returns f32; bf16 applies to inputs only)
  float* out_logits = (float*)d_out;
  float* out_embed  = out_logits + (size_t)B * TT * VV;
  float* out_trace  = out_embed + (size_t)B * DD;

  k_csinit  <<<(TT * NPAIR) / 256, 256, 0, stream>>>(cs);
  k_embed_ln<<<B * TT, 256, 0, stream>>>(ids, tbl, x);
  for (int l = 0; l < NLAYER; ++l) {
    k_enc    <<<dim3(NN / 64, TT / 64, B * NH), 256, 0, stream>>>(x, enc, xsp);
    k_scores <<<dim3(TT / 64, TT / 64, B * NH), 256, 0, stream>>>(xsp, cs, sc);
    k_ykv    <<<dim3(DD / 64, TT / 64, B * NH), 256, 0, stream>>>(sc, x, ykv);
    k_ln_rows<<<B * NH * TT, 256, 0, stream>>>(ykv);
    k_ysp_xy <<<dim3(NN / 64, TT / 64, B * NH), 256, 0, stream>>>(ykv, encv, xsp);
    k_ymlp   <<<dim3(DD / 64, TT / 64, B * NH), 256, 0, stream>>>(xsp, dec, ym4);
    k_ln2    <<<B * TT, 256, 0, stream>>>(x, ym4);
  }
  k_trace    <<<(B * NH * NN) / 256, 256, 0, stream>>>(xsp, out_trace);
  k_logits   <<<B * TT, 256, 0, stream>>>(x, lmh, out_logits);
  k_embedding<<<(B * DD) / 256, 256, 0, stream>>>(x, out_embed);
}

// Round 7
// 3671.954 us; speedup vs baseline: 1.6447x; 1.6447x over previous
//
#include <hip/hip_runtime.h>
#include <hip/hip_bf16.h>

#define TT 512
#define DD 256
#define NH 4
#define NN 4096
#define VV 256
#define NLAYER 6

typedef __attribute__((ext_vector_type(8))) short bf16x8;
typedef __attribute__((ext_vector_type(4))) float f32x4;
typedef __attribute__((ext_vector_type(8))) unsigned short us8;
typedef __attribute__((ext_vector_type(4))) unsigned short us4;

// f32 -> bf16 bits, round-to-nearest-even
__device__ __forceinline__ unsigned short f2bf(float f) {
  unsigned int u = __float_as_uint(f);
  return (unsigned short)((u + 0x7FFFu + ((u >> 16) & 1u)) >> 16);
}

// ---------------- block-wide sum over 256 threads ----------------
__device__ __forceinline__ float block_sum_256(float v) {
  __shared__ float s[4];
  #pragma unroll
  for (int o = 32; o > 0; o >>= 1) v += __shfl_down(v, o);
  int lane = threadIdx.x & 63, wid = threadIdx.x >> 6;
  if (lane == 0) s[wid] = v;
  __syncthreads();
  float r = s[0] + s[1] + s[2] + s[3];
  __syncthreads();
  return r;
}

// ---------------- 64x64 f32 tile GEMM: C(64x64) += A(64xK) * B(Kx64) ----------------
__device__ __forceinline__ void gemm64(const float* __restrict__ A, int lda,
                                       const float* __restrict__ B, int ldb,
                                       int K, float acc[4][4]) {
  __shared__ float As[16][65];
  __shared__ float Bs[16][64];
  const int tid = threadIdx.x;
  const int tx = tid & 15, ty = tid >> 4;
  const int am = tid >> 2, ak = (tid & 3) << 2;
  const int bk = tid >> 4, bn = (tid & 15) << 2;
  for (int k0 = 0; k0 < K; k0 += 16) {
    float4 av = *(const float4*)(A + am * lda + k0 + ak);
    float4 bv = *(const float4*)(B + (k0 + bk) * ldb + bn);
    As[ak + 0][am] = av.x; As[ak + 1][am] = av.y;
    As[ak + 2][am] = av.z; As[ak + 3][am] = av.w;
    *(float4*)(&Bs[bk][bn]) = bv;
    __syncthreads();
    #pragma unroll
    for (int k = 0; k < 16; ++k) {
      float a0 = As[k][(ty << 2) + 0], a1 = As[k][(ty << 2) + 1];
      float a2 = As[k][(ty << 2) + 2], a3 = As[k][(ty << 2) + 3];
      float4 b4 = *(const float4*)(&Bs[k][tx << 2]);
      acc[0][0] = fmaf(a0, b4.x, acc[0][0]); acc[0][1] = fmaf(a0, b4.y, acc[0][1]);
      acc[0][2] = fmaf(a0, b4.z, acc[0][2]); acc[0][3] = fmaf(a0, b4.w, acc[0][3]);
      acc[1][0] = fmaf(a1, b4.x, acc[1][0]); acc[1][1] = fmaf(a1, b4.y, acc[1][1]);
      acc[1][2] = fmaf(a1, b4.z, acc[1][2]); acc[1][3] = fmaf(a1, b4.w, acc[1][3]);
      acc[2][0] = fmaf(a2, b4.x, acc[2][0]); acc[2][1] = fmaf(a2, b4.y, acc[2][1]);
      acc[2][2] = fmaf(a2, b4.z, acc[2][2]); acc[2][3] = fmaf(a2, b4.w, acc[2][3]);
      acc[3][0] = fmaf(a3, b4.x, acc[3][0]); acc[3][1] = fmaf(a3, b4.y, acc[3][1]);
      acc[3][2] = fmaf(a3, b4.z, acc[3][2]); acc[3][3] = fmaf(a3, b4.w, acc[3][3]);
    }
    __syncthreads();
  }
}

// ---------------- kernels ----------------

// x[b,t,:] = LN(embed_table[ids[b,t], :]) — ids may be int64 or int32 words
__global__ __launch_bounds__(256) void k_embed_ln(const int* __restrict__ idw,
                                                  const float* __restrict__ tbl,
                                                  float* __restrict__ x) {
  __shared__ int s_id;
  int row = blockIdx.x, tid = threadIdx.x;
  if (tid == 0) {
    bool is64 = true;
    for (int i = 1; i < 64; i += 2)
      if (idw[i] != 0) { is64 = false; break; }
    s_id = is64 ? idw[2 * row] : idw[row];
  }
  __syncthreads();
  int id = s_id;
  float v = tbl[(size_t)id * DD + tid];
  float mu = block_sum_256(v) * (1.0f / DD);
  float d = v - mu;
  float var = block_sum_256(d * d) * (1.0f / DD);
  x[(size_t)row * DD + tid] = d * rsqrtf(var + 1e-5f);
}

// xsp = relu(x @ enc[h])  (f32), and qr = bf16(rope(xsp))
__global__ __launch_bounds__(256) void k_enc(const float* __restrict__ x,
                                             const float* __restrict__ enc,
                                             float* __restrict__ xsp,
                                             unsigned short* __restrict__ qr) {
  const int bh = blockIdx.z, b = bh >> 2, h = bh & 3;
  const int m0 = blockIdx.y * 64, n0 = blockIdx.x * 64;
  float acc[4][4] = {};
  gemm64(x + (size_t)b * TT * DD + (size_t)m0 * DD, DD,
         enc + (size_t)h * DD * NN + n0, NN, DD, acc);
  const int tx = threadIdx.x & 15, ty = threadIdx.x >> 4;
  const size_t base = (size_t)bh * TT * NN;
  const int nc = n0 + (tx << 2);          // pair bases nc and nc+2
  const float INV2PI = 0.15915494309189535f;
  const float TWOPI = 6.283185307179586f;
  const float f0 = exp2f(-16.0f * (float)nc / (float)NN) * INV2PI;
  const float f1 = exp2f(-16.0f * (float)(nc + 2) / (float)NN) * INV2PI;
  #pragma unroll
  for (int i = 0; i < 4; ++i) {
    int t = m0 + (ty << 2) + i;
    float v0 = fmaxf(acc[i][0], 0.0f), v1 = fmaxf(acc[i][1], 0.0f);
    float v2 = fmaxf(acc[i][2], 0.0f), v3 = fmaxf(acc[i][3], 0.0f);
    float4 sv = {v0, v1, v2, v3};
    *(float4*)(xsp + base + (size_t)t * NN + nc) = sv;
    float ph0 = fmodf((float)t * f0, 1.0f) * TWOPI;
    float ph1 = fmodf((float)t * f1, 1.0f) * TWOPI;
    float s0, c0, s1, c1;
    sincosf(ph0, &s0, &c0);
    sincosf(ph1, &s1, &c1);
    us4 qv;
    qv.x = f2bf(v0 * c0 - v1 * s0);
    qv.y = f2bf(v1 * c0 + v0 * s0);
    qv.z = f2bf(v2 * c1 - v3 * s1);
    qv.w = f2bf(v3 * c1 + v2 * s1);
    *(us4*)(qr + base + (size_t)t * NN + nc) = qv;
  }
}

// scores[t,s] = (s < t) ? qr[t,:]·qr[s,:] : 0    — bf16 MFMA
// 64x64 tile per block, 4 waves; wave w computes rows [w*16, w*16+16) x 64 cols.
__global__ __launch_bounds__(256) void k_scores(const unsigned short* __restrict__ qr,
                                                float* __restrict__ sc) {
  const int bh = blockIdx.z;
  const int m0 = blockIdx.y * 64, n0 = blockIdx.x * 64;
  const int tid = threadIdx.x;
  float* C = sc + (size_t)bh * TT * TT;
  if (n0 > m0) {  // tile fully masked: write zeros (ws is poisoned)
    float4 z = {0.0f, 0.0f, 0.0f, 0.0f};
    const int r = tid >> 2, c4 = (tid & 3) << 4;
    #pragma unroll
    for (int j = 0; j < 4; ++j)
      *(float4*)(C + (size_t)(m0 + r) * TT + n0 + c4 + j * 4) = z;
    return;
  }
  __shared__ unsigned short As[64][40];  // stride 40: rows r,r+8 alias -> 2-way (free)
  __shared__ unsigned short Bs[64][40];
  const unsigned short* Q = qr + (size_t)bh * TT * NN;
  const int lane = tid & 63, wave = tid >> 6;
  const int srow = tid >> 2, sk = (tid & 3) << 3;  // staging: 16B per thread per tile
  const int fm = lane & 15, fq = lane >> 4;        // fragment row/quad
  f32x4 acc[4] = {};
  for (int k0 = 0; k0 < NN; k0 += 32) {
    *(us8*)(&As[srow][sk]) = *(const us8*)(Q + (size_t)(m0 + srow) * NN + k0 + sk);
    *(us8*)(&Bs[srow][sk]) = *(const us8*)(Q + (size_t)(n0 + srow) * NN + k0 + sk);
    __syncthreads();
    bf16x8 a = *(const bf16x8*)(&As[wave * 16 + fm][fq << 3]);
    #pragma unroll
    for (int nt = 0; nt < 4; ++nt) {
      bf16x8 bfr = *(const bf16x8*)(&Bs[nt * 16 + fm][fq << 3]);
      acc[nt] = __builtin_amdgcn_mfma_f32_16x16x32_bf16(a, bfr, acc[nt], 0, 0, 0);
    }
    __syncthreads();
  }
  // C/D layout: col = lane&15, row = quad*4 + reg
  const int trow = m0 + wave * 16 + (fq << 2);
  #pragma unroll
  for (int nt = 0; nt < 4; ++nt) {
    int s = n0 + nt * 16 + fm;
    #pragma unroll
    for (int r = 0; r < 4; ++r) {
      int t = trow + r;
      C[(size_t)t * TT + s] = (s < t) ? acc[nt][r] : 0.0f;
    }
  }
}

// ykv = scores @ x   (pre-LN)
__global__ __launch_bounds__(256) void k_ykv(const float* __restrict__ sc,
                                             const float* __restrict__ x,
                                             float* __restrict__ ykv) {
  const int bh = blockIdx.z, b = bh >> 2;
  const int m0 = blockIdx.y * 64, n0 = blockIdx.x * 64;
  float acc[4][4] = {};
  gemm64(sc + (size_t)bh * TT * TT + (size_t)m0 * TT, TT,
         x + (size_t)b * TT * DD + n0, DD, TT, acc);
  const int tx = threadIdx.x & 15, ty = threadIdx.x >> 4;
  float* C = ykv + (size_t)bh * TT * DD;
  #pragma unroll
  for (int i = 0; i < 4; ++i) {
    float4 v = {acc[i][0], acc[i][1], acc[i][2], acc[i][3]};
    *(float4*)(C + (size_t)(m0 + (ty << 2) + i) * DD + n0 + (tx << 2)) = v;
  }
}

// in-place LN over rows of width 256
__global__ __launch_bounds__(256) void k_ln_rows(float* __restrict__ p) {
  int row = blockIdx.x, tid = threadIdx.x;
  float v = p[(size_t)row * DD + tid];
  float mu = block_sum_256(v) * (1.0f / DD);
  float d = v - mu;
  float var = block_sum_256(d * d) * (1.0f / DD);
  p[(size_t)row * DD + tid] = d * rsqrtf(var + 1e-5f);
}

// xsp = xsp * relu(ykv @ encv[h])   (in-place: xy overwrites x_sparse)
__global__ __launch_bounds__(256) void k_ysp_xy(const float* __restrict__ ykv,
                                                const float* __restrict__ encv,
                                                float* __restrict__ xsp) {
  const int bh = blockIdx.z, h = bh & 3;
  const int m0 = blockIdx.y * 64, n0 = blockIdx.x * 64;
  float acc[4][4] = {};
  gemm64(ykv + (size_t)bh * TT * DD + (size_t)m0 * DD, DD,
         encv + (size_t)h * DD * NN + n0, NN, DD, acc);
  const int tx = threadIdx.x & 15, ty = threadIdx.x >> 4;
  const size_t base = (size_t)bh * TT * NN;
  #pragma unroll
  for (int i = 0; i < 4; ++i) {
    int t = m0 + (ty << 2) + i;
    size_t off = base + (size_t)t * NN + n0 + (tx << 2);
    float4 xv = *(const float4*)(xsp + off);
    float4 o;
    o.x = xv.x * fmaxf(acc[i][0], 0.0f);
    o.y = xv.y * fmaxf(acc[i][1], 0.0f);
    o.z = xv.z * fmaxf(acc[i][2], 0.0f);
    o.w = xv.w * fmaxf(acc[i][3], 0.0f);
    *(float4*)(xsp + off) = o;
  }
}

// ym4[b,h] = xy[b,h] @ dec[h]   (per-head partials, summed in k_ln2)
__global__ __launch_bounds__(256) void k_ymlp(const float* __restrict__ xy,
                                              const float* __restrict__ dec,
                                              float* __restrict__ ym4) {
  const int bh = blockIdx.z, h = bh & 3;
  const int m0 = blockIdx.y * 64, n0 = blockIdx.x * 64;
  float acc[4][4] = {};
  gemm64(xy + (size_t)bh * TT * NN + (size_t)m0 * NN, NN,
         dec + (size_t)h * NN * DD + n0, DD, NN, acc);
  const int tx = threadIdx.x & 15, ty = threadIdx.x >> 4;
  float* C = ym4 + (size_t)bh * TT * DD;
  #pragma unroll
  for (int i = 0; i < 4; ++i) {
    float4 v = {acc[i][0], acc[i][1], acc[i][2], acc[i][3]};
    *(float4*)(C + (size_t)(m0 + (ty << 2) + i) * DD + n0 + (tx << 2)) = v;
  }
}

// x = LN(x + LN(sum_h ym4))
__global__ __launch_bounds__(256) void k_ln2(float* __restrict__ x,
                                             const float* __restrict__ ym4) {
  int row = blockIdx.x, tid = threadIdx.x;
  int b = row >> 9, t = row & 511;
  float y = 0.0f;
  #pragma unroll
  for (int h = 0; h < 4; ++h)
    y += ym4[(size_t)((b * 4 + h) * TT + t) * DD + tid];
  float mu = block_sum_256(y) * (1.0f / DD);
  float d = y - mu;
  float var = block_sum_256(d * d) * (1.0f / DD);
  float ly = d * rsqrtf(var + 1e-5f);
  float xv = x[(size_t)row * DD + tid] + ly;
  float mu2 = block_sum_256(xv) * (1.0f / DD);
  float d2 = xv - mu2;
  float var2 = block_sum_256(d2 * d2) * (1.0f / DD);
  x[(size_t)row * DD + tid] = d2 * rsqrtf(var2 + 1e-5f);
}

// neuron_trace[b, h*N+n] = mean_t xy[b,h,t,n]   (f32 output)
__global__ __launch_bounds__(256) void k_trace(const float* __restrict__ xy,
                                               float* __restrict__ out) {
  int idx = blockIdx.x * 256 + threadIdx.x;
  int b = idx >> 14, c = idx & 16383;
  int h = c >> 12, n = c & 4095;
  size_t base = (size_t)(b * 4 + h) * TT * NN + n;
  float s = 0.0f;
  for (int t = 0; t < TT; ++t) s += xy[base + (size_t)t * NN];
  out[idx] = s * (1.0f / TT);
}

// logits[b,t,:] = x[b,t,:] @ lm_head   (f32 output)
__global__ __launch_bounds__(256) void k_logits(const float* __restrict__ x,
                                                const float* __restrict__ W,
                                                float* __restrict__ out) {
  __shared__ float xs[DD];
  int row = blockIdx.x, tid = threadIdx.x;
  xs[tid] = x[(size_t)row * DD + tid];
  __syncthreads();
  float s = 0.0f;
  #pragma unroll 8
  for (int d = 0; d < DD; ++d) s = fmaf(xs[d], W[(size_t)d * VV + tid], s);
  out[(size_t)row * VV + tid] = s;
}

// embedding[b,d] = mean_t x[b,t,d]   (f32 output)
__global__ __launch_bounds__(256) void k_embedding(const float* __restrict__ x,
                                                   float* __restrict__ out) {
  int idx = blockIdx.x * 256 + threadIdx.x;
  int b = idx >> 8, d = idx & 255;
  float s = 0.0f;
  for (int t = 0; t < TT; ++t) s += x[(size_t)(b * TT + t) * DD + d];
  out[idx] = s * (1.0f / TT);
}

extern "C" void kernel_launch(void* const* d_in, const int* in_sizes, int n_in,
                              void* d_out, int out_size, void* d_ws, size_t ws_size,
                              hipStream_t stream) {
  const int*   ids  = (const int*)d_in[0];
  const float* tbl  = (const float*)d_in[1];
  const float* enc  = (const float*)d_in[2];
  const float* encv = (const float*)d_in[3];
  const float* dec  = (const float*)d_in[4];
  const float* lmh  = (const float*)d_in[5];
  const int B = 2;

  // workspace: ~117 MiB
  float*  ws  = (float*)d_ws;
  float*  x   = ws;                                  //    262,144 f
  float*  xsp = x   + (size_t)B * TT * DD;           // 16,777,216 f (x_sparse, then xy in-place)
  float*  sc  = xsp + (size_t)B * NH * TT * NN;      //  2,097,152 f
  float*  ykv = sc  + (size_t)B * NH * TT * TT;      //  1,048,576 f
  float*  ym4 = ykv + (size_t)B * NH * TT * DD;      //  1,048,576 f
  unsigned short* qr = (unsigned short*)(ym4 + (size_t)B * NH * TT * DD); // 16,777,216 us = 32 MiB

  // outputs are float32
  float* out_logits = (float*)d_out;
  float* out_embed  = out_logits + (size_t)B * TT * VV;
  float* out_trace  = out_embed + (size_t)B * DD;

  k_embed_ln<<<B * TT, 256, 0, stream>>>(ids, tbl, x);
  for (int l = 0; l < NLAYER; ++l) {
    k_enc    <<<dim3(NN / 64, TT / 64, B * NH), 256, 0, stream>>>(x, enc, xsp, qr);
    k_scores <<<dim3(TT / 64, TT / 64, B * NH), 256, 0, stream>>>(qr, sc);
    k_ykv    <<<dim3(DD / 64, TT / 64, B * NH), 256, 0, stream>>>(sc, x, ykv);
    k_ln_rows<<<B * NH * TT, 256, 0, stream>>>(ykv);
    k_ysp_xy <<<dim3(NN / 64, TT / 64, B * NH), 256, 0, stream>>>(ykv, encv, xsp);
    k_ymlp   <<<dim3(DD / 64, TT / 64, B * NH), 256, 0, stream>>>(xsp, dec, ym4);
    k_ln2    <<<B * TT, 256, 0, stream>>>(x, ym4);
  }
  k_trace    <<<(B * NH * NN) / 256, 256, 0, stream>>>(xsp, out_trace);
  k_logits   <<<B * TT, 256, 0, stream>>>(x, lmh, out_logits);
  k_embedding<<<(B * DD) / 256, 256, 0, stream>>>(x, out_embed);
}

// Round 8
// 1564.598 us; speedup vs baseline: 3.8600x; 2.3469x over previous
//
#include <hip/hip_runtime.h>
#include <hip/hip_bf16.h>

#define TT 512
#define DD 256
#define NH 4
#define NN 4096
#define VV 256
#define NLAYER 6
#define BB 2
#define BH (BB * NH)

typedef __attribute__((ext_vector_type(8))) short bf16x8;
typedef __attribute__((ext_vector_type(4))) float f32x4;
typedef __attribute__((ext_vector_type(8))) unsigned short us8;

// f32 -> bf16 bits, round-to-nearest-even
__device__ __forceinline__ unsigned short f2bf(float f) {
  unsigned int u = __float_as_uint(f);
  return (unsigned short)((u + 0x7FFFu + ((u >> 16) & 1u)) >> 16);
}
__device__ __forceinline__ float bf2f(unsigned short h) {
  return __uint_as_float((unsigned int)h << 16);
}

// ---------------- block-wide sum over 256 threads ----------------
__device__ __forceinline__ float block_sum_256(float v) {
  __shared__ float s[4];
  #pragma unroll
  for (int o = 32; o > 0; o >>= 1) v += __shfl_down(v, o);
  int lane = threadIdx.x & 63, wid = threadIdx.x >> 6;
  if (lane == 0) s[wid] = v;
  __syncthreads();
  float r = s[0] + s[1] + s[2] + s[3];
  __syncthreads();
  return r;
}

// ---- 64x64 MFMA tile: C = A(64xK) * B(64xK)^T, bf16 inputs, f32 acc ----
// Verified pattern (R7 k_scores): both fragments loaded K-contiguous.
// wave w owns rows [w*16,w*16+16); acc[nt] covers cols [nt*16, nt*16+16).
__device__ __forceinline__ void mfma_tile_bt(const unsigned short* __restrict__ A, int lda,
                                             const unsigned short* __restrict__ B, int ldb,
                                             int K, f32x4 acc[4],
                                             unsigned short As[64][40],
                                             unsigned short Bs[64][40]) {
  const int tid = threadIdx.x;
  const int lane = tid & 63, wave = tid >> 6;
  const int srow = tid >> 2, sk = (tid & 3) << 3;
  const int fm = lane & 15, fq = lane >> 4;
  for (int k0 = 0; k0 < K; k0 += 32) {
    *(us8*)(&As[srow][sk]) = *(const us8*)(A + (size_t)srow * lda + k0 + sk);
    *(us8*)(&Bs[srow][sk]) = *(const us8*)(B + (size_t)srow * ldb + k0 + sk);
    __syncthreads();
    bf16x8 a = *(const bf16x8*)(&As[wave * 16 + fm][fq << 3]);
    #pragma unroll
    for (int nt = 0; nt < 4; ++nt) {
      bf16x8 b = *(const bf16x8*)(&Bs[nt * 16 + fm][fq << 3]);
      acc[nt] = __builtin_amdgcn_mfma_f32_16x16x32_bf16(a, b, acc[nt], 0, 0, 0);
    }
    __syncthreads();
  }
}
// C/D layout: col = n0 + nt*16 + (lane&15); row = m0 + wave*16 + (lane>>4)*4 + reg

// ---------------- transpose-cast: out[c][r] = bf16(in[r][c]) ----------------
__global__ __launch_bounds__(256) void k_tcast(const float* __restrict__ in,
                                               unsigned short* __restrict__ out,
                                               int R, int C) {
  __shared__ float tile[64][65];
  const size_t zoff = (size_t)blockIdx.z * R * C;
  const int r0 = blockIdx.y * 64, c0 = blockIdx.x * 64;
  const int cl = threadIdx.x & 63, r4 = threadIdx.x >> 6;
  #pragma unroll 4
  for (int i = 0; i < 16; ++i) {
    int rl = r4 * 16 + i;
    tile[rl][cl] = in[zoff + (size_t)(r0 + rl) * C + c0 + cl];
  }
  __syncthreads();
  #pragma unroll 4
  for (int i = 0; i < 16; ++i) {
    int ccl = r4 * 16 + i;
    out[zoff + (size_t)(c0 + ccl) * R + r0 + cl] = f2bf(tile[cl][ccl]);
  }
}

// x (f32, [B][T][D]) -> xbf ([B][T][D] bf16) and xTbf ([B][D][T] bf16)
__global__ __launch_bounds__(256) void k_xcast(const float* __restrict__ x,
                                               unsigned short* __restrict__ xbf,
                                               unsigned short* __restrict__ xTbf) {
  __shared__ float tile[64][65];
  const int b = blockIdx.z;
  const float* in = x + (size_t)b * TT * DD;
  unsigned short* oR = xbf + (size_t)b * TT * DD;
  unsigned short* oT = xTbf + (size_t)b * DD * TT;
  const int r0 = blockIdx.y * 64, c0 = blockIdx.x * 64;
  const int cl = threadIdx.x & 63, r4 = threadIdx.x >> 6;
  #pragma unroll 4
  for (int i = 0; i < 16; ++i) {
    int rl = r4 * 16 + i;
    float v = in[(size_t)(r0 + rl) * DD + c0 + cl];
    tile[rl][cl] = v;
    oR[(size_t)(r0 + rl) * DD + c0 + cl] = f2bf(v);
  }
  __syncthreads();
  #pragma unroll 4
  for (int i = 0; i < 16; ++i) {
    int ccl = r4 * 16 + i;
    oT[(size_t)(c0 + ccl) * TT + r0 + cl] = f2bf(tile[cl][ccl]);
  }
}

// ---------------- kernels ----------------

// x[b,t,:] = LN(embed_table[ids[b,t], :]) — ids may be int64 or int32 words
__global__ __launch_bounds__(256) void k_embed_ln(const int* __restrict__ idw,
                                                  const float* __restrict__ tbl,
                                                  float* __restrict__ x) {
  __shared__ int s_id;
  int row = blockIdx.x, tid = threadIdx.x;
  if (tid == 0) {
    bool is64 = true;
    for (int i = 1; i < 64; i += 2)
      if (idw[i] != 0) { is64 = false; break; }
    s_id = is64 ? idw[2 * row] : idw[row];
  }
  __syncthreads();
  int id = s_id;
  float v = tbl[(size_t)id * DD + tid];
  float mu = block_sum_256(v) * (1.0f / DD);
  float d = v - mu;
  float var = block_sum_256(d * d) * (1.0f / DD);
  x[(size_t)row * DD + tid] = d * rsqrtf(var + 1e-5f);
}

// xsp_bf = bf16(relu(x @ enc[h])); qr = bf16(rope(relu)) — MFMA + shfl RoPE
__global__ __launch_bounds__(256) void k_enc(const unsigned short* __restrict__ xbf,
                                             const unsigned short* __restrict__ encT,
                                             unsigned short* __restrict__ xsp,
                                             unsigned short* __restrict__ qr) {
  __shared__ unsigned short As[64][40], Bs[64][40];
  const int bh = blockIdx.z, b = bh >> 2, h = bh & 3;
  const int m0 = blockIdx.y * 64, n0 = blockIdx.x * 64;
  f32x4 acc[4] = {};
  mfma_tile_bt(xbf + (size_t)b * TT * DD + (size_t)m0 * DD, DD,
               encT + (size_t)h * NN * DD + (size_t)n0 * DD, DD, DD, acc, As, Bs);
  const int lane = threadIdx.x & 63, wave = threadIdx.x >> 6;
  const int fm = lane & 15, fq = lane >> 4;
  const int trow = m0 + wave * 16 + (fq << 2);
  const size_t base = (size_t)bh * TT * NN;
  const float INV2PI = 0.15915494309189535f;
  const float TWOPI = 6.283185307179586f;
  const int odd = fm & 1;
  #pragma unroll
  for (int nt = 0; nt < 4; ++nt) {
    const int n = n0 + nt * 16 + fm;
    const int ne = n & ~1;
    const float f = exp2f(-16.0f * (float)ne / (float)NN) * INV2PI;
    #pragma unroll
    for (int r = 0; r < 4; ++r) {
      const int t = trow + r;
      float v = fmaxf(acc[nt][r], 0.0f);
      float vp = __shfl_xor(v, 1);  // partner of the RoPE pair
      size_t off = base + (size_t)t * NN + n;
      xsp[off] = f2bf(v);
      float ph = fmodf((float)t * f, 1.0f) * TWOPI;
      float sn, cn;
      sincosf(ph, &sn, &cn);
      qr[off] = f2bf(v * cn + (odd ? vp : -vp) * sn);
    }
  }
}

// sc_bf[t,s] = bf16((s < t) ? qr[t,:]·qr[s,:] : 0) — bf16 MFMA
__global__ __launch_bounds__(256) void k_scores(const unsigned short* __restrict__ qr,
                                                unsigned short* __restrict__ sc) {
  const int bh = blockIdx.z;
  const int m0 = blockIdx.y * 64, n0 = blockIdx.x * 64;
  const int tid = threadIdx.x;
  unsigned short* C = sc + (size_t)bh * TT * TT;
  if (n0 > m0) {  // fully masked tile: write bf16 zeros
    us8 z = {0, 0, 0, 0, 0, 0, 0, 0};
    const int r = tid >> 2, c16 = (tid & 3) << 4;
    *(us8*)(C + (size_t)(m0 + r) * TT + n0 + c16) = z;
    *(us8*)(C + (size_t)(m0 + r) * TT + n0 + c16 + 8) = z;
    return;
  }
  __shared__ unsigned short As[64][40], Bs[64][40];
  const unsigned short* Q = qr + (size_t)bh * TT * NN;
  f32x4 acc[4] = {};
  mfma_tile_bt(Q + (size_t)m0 * NN, NN, Q + (size_t)n0 * NN, NN, NN, acc, As, Bs);
  const int lane = tid & 63, wave = tid >> 6;
  const int fm = lane & 15, fq = lane >> 4;
  const int trow = m0 + wave * 16 + (fq << 2);
  #pragma unroll
  for (int nt = 0; nt < 4; ++nt) {
    int s = n0 + nt * 16 + fm;
    #pragma unroll
    for (int r = 0; r < 4; ++r) {
      int t = trow + r;
      C[(size_t)t * TT + s] = f2bf((s < t) ? acc[nt][r] : 0.0f);
    }
  }
}

// ykv = sc_bf @ x  (pre-LN, f32 out) — MFMA, BT = xTbf
__global__ __launch_bounds__(256) void k_ykv(const unsigned short* __restrict__ sc,
                                             const unsigned short* __restrict__ xTbf,
                                             float* __restrict__ ykv) {
  __shared__ unsigned short As[64][40], Bs[64][40];
  const int bh = blockIdx.z, b = bh >> 2;
  const int m0 = blockIdx.y * 64, n0 = blockIdx.x * 64;
  f32x4 acc[4] = {};
  mfma_tile_bt(sc + (size_t)bh * TT * TT + (size_t)m0 * TT, TT,
               xTbf + (size_t)b * DD * TT + (size_t)n0 * TT, TT, TT, acc, As, Bs);
  const int lane = threadIdx.x & 63, wave = threadIdx.x >> 6;
  const int fm = lane & 15, fq = lane >> 4;
  const int trow = m0 + wave * 16 + (fq << 2);
  float* C = ykv + (size_t)bh * TT * DD;
  #pragma unroll
  for (int nt = 0; nt < 4; ++nt) {
    int d = n0 + nt * 16 + fm;
    #pragma unroll
    for (int r = 0; r < 4; ++r)
      C[(size_t)(trow + r) * DD + d] = acc[nt][r];
  }
}

// in-place LN over rows of width 256, also emit bf16 copy
__global__ __launch_bounds__(256) void k_ln_rows(float* __restrict__ p,
                                                 unsigned short* __restrict__ pbf) {
  int row = blockIdx.x, tid = threadIdx.x;
  float v = p[(size_t)row * DD + tid];
  float mu = block_sum_256(v) * (1.0f / DD);
  float d = v - mu;
  float var = block_sum_256(d * d) * (1.0f / DD);
  float r = d * rsqrtf(var + 1e-5f);
  p[(size_t)row * DD + tid] = r;
  pbf[(size_t)row * DD + tid] = f2bf(r);
}

// xy_bf = xsp_bf * relu(ykv_bf @ encv[h]) — MFMA
__global__ __launch_bounds__(256) void k_ysp_xy(const unsigned short* __restrict__ ykvbf,
                                                const unsigned short* __restrict__ encvT,
                                                const unsigned short* __restrict__ xsp,
                                                unsigned short* __restrict__ xy) {
  __shared__ unsigned short As[64][40], Bs[64][40];
  const int bh = blockIdx.z, h = bh & 3;
  const int m0 = blockIdx.y * 64, n0 = blockIdx.x * 64;
  f32x4 acc[4] = {};
  mfma_tile_bt(ykvbf + (size_t)bh * TT * DD + (size_t)m0 * DD, DD,
               encvT + (size_t)h * NN * DD + (size_t)n0 * DD, DD, DD, acc, As, Bs);
  const int lane = threadIdx.x & 63, wave = threadIdx.x >> 6;
  const int fm = lane & 15, fq = lane >> 4;
  const int trow = m0 + wave * 16 + (fq << 2);
  const size_t base = (size_t)bh * TT * NN;
  #pragma unroll
  for (int nt = 0; nt < 4; ++nt) {
    int n = n0 + nt * 16 + fm;
    #pragma unroll
    for (int r = 0; r < 4; ++r) {
      size_t off = base + (size_t)(trow + r) * NN + n;
      float prod = bf2f(xsp[off]) * fmaxf(acc[nt][r], 0.0f);
      xy[off] = f2bf(prod);
    }
  }
}

// ym4[b,h] = xy_bf[b,h] @ dec[h] (f32 out) — MFMA, K=4096
__global__ __launch_bounds__(256) void k_ymlp(const unsigned short* __restrict__ xy,
                                              const unsigned short* __restrict__ decT,
                                              float* __restrict__ ym4) {
  __shared__ unsigned short As[64][40], Bs[64][40];
  const int bh = blockIdx.z, h = bh & 3;
  const int m0 = blockIdx.y * 64, n0 = blockIdx.x * 64;
  f32x4 acc[4] = {};
  mfma_tile_bt(xy + (size_t)bh * TT * NN + (size_t)m0 * NN, NN,
               decT + (size_t)h * DD * NN + (size_t)n0 * NN, NN, NN, acc, As, Bs);
  const int lane = threadIdx.x & 63, wave = threadIdx.x >> 6;
  const int fm = lane & 15, fq = lane >> 4;
  const int trow = m0 + wave * 16 + (fq << 2);
  float* C = ym4 + (size_t)bh * TT * DD;
  #pragma unroll
  for (int nt = 0; nt < 4; ++nt) {
    int d = n0 + nt * 16 + fm;
    #pragma unroll
    for (int r = 0; r < 4; ++r)
      C[(size_t)(trow + r) * DD + d] = acc[nt][r];
  }
}

// x = LN(x + LN(sum_h ym4))
__global__ __launch_bounds__(256) void k_ln2(float* __restrict__ x,
                                             const float* __restrict__ ym4) {
  int row = blockIdx.x, tid = threadIdx.x;
  int b = row >> 9, t = row & 511;
  float y = 0.0f;
  #pragma unroll
  for (int h = 0; h < 4; ++h)
    y += ym4[(size_t)((b * 4 + h) * TT + t) * DD + tid];
  float mu = block_sum_256(y) * (1.0f / DD);
  float d = y - mu;
  float var = block_sum_256(d * d) * (1.0f / DD);
  float ly = d * rsqrtf(var + 1e-5f);
  float xv = x[(size_t)row * DD + tid] + ly;
  float mu2 = block_sum_256(xv) * (1.0f / DD);
  float d2 = xv - mu2;
  float var2 = block_sum_256(d2 * d2) * (1.0f / DD);
  x[(size_t)row * DD + tid] = d2 * rsqrtf(var2 + 1e-5f);
}

// neuron_trace[b, h*N+n] = mean_t xy_bf[b,h,t,n]   (f32 output)
__global__ __launch_bounds__(256) void k_trace(const unsigned short* __restrict__ xy,
                                               float* __restrict__ out) {
  int idx = blockIdx.x * 256 + threadIdx.x;
  int b = idx >> 14, c = idx & 16383;
  int h = c >> 12, n = c & 4095;
  size_t base = (size_t)(b * 4 + h) * TT * NN + n;
  float s = 0.0f;
  for (int t = 0; t < TT; ++t) s += bf2f(xy[base + (size_t)t * NN]);
  out[idx] = s * (1.0f / TT);
}

// logits[b,t,:] = x[b,t,:] @ lm_head   (f32 output)
__global__ __launch_bounds__(256) void k_logits(const float* __restrict__ x,
                                                const float* __restrict__ W,
                                                float* __restrict__ out) {
  __shared__ float xs[DD];
  int row = blockIdx.x, tid = threadIdx.x;
  xs[tid] = x[(size_t)row * DD + tid];
  __syncthreads();
  float s = 0.0f;
  #pragma unroll 8
  for (int d = 0; d < DD; ++d) s = fmaf(xs[d], W[(size_t)d * VV + tid], s);
  out[(size_t)row * VV + tid] = s;
}

// embedding[b,d] = mean_t x[b,t,d]   (f32 output)
__global__ __launch_bounds__(256) void k_embedding(const float* __restrict__ x,
                                                   float* __restrict__ out) {
  int idx = blockIdx.x * 256 + threadIdx.x;
  int b = idx >> 8, d = idx & 255;
  float s = 0.0f;
  for (int t = 0; t < TT; ++t) s += x[(size_t)(b * TT + t) * DD + d];
  out[idx] = s * (1.0f / TT);
}

extern "C" void kernel_launch(void* const* d_in, const int* in_sizes, int n_in,
                              void* d_out, int out_size, void* d_ws, size_t ws_size,
                              hipStream_t stream) {
  const int*   ids  = (const int*)d_in[0];
  const float* tbl  = (const float*)d_in[1];
  const float* enc  = (const float*)d_in[2];
  const float* encv = (const float*)d_in[3];
  const float* dec  = (const float*)d_in[4];
  const float* lmh  = (const float*)d_in[5];

  // workspace layout (float units), total ~104 MiB
  float* ws   = (float*)d_ws;
  float* x    = ws;                                   //   262,144 f
  unsigned short* scbf = (unsigned short*)(x + 262144);          // 2,097,152 us
  float* ykv  = (float*)(scbf + 2097152);             // 1,048,576 f
  unsigned short* ykvbf = (unsigned short*)(ykv + 1048576);      // 1,048,576 us
  float* ym4  = (float*)(ykvbf + 1048576);            // 1,048,576 f
  unsigned short* xbf  = (unsigned short*)(ym4 + 1048576);       //   262,144 us
  unsigned short* xTbf = xbf + 262144;                           //   262,144 us
  unsigned short* encT  = xTbf + 262144;                         // 4,194,304 us
  unsigned short* encvT = encT + 4194304;                        // 4,194,304 us
  unsigned short* decT  = encvT + 4194304;                       // 4,194,304 us
  unsigned short* xspbf = decT + 4194304;                        // 16,777,216 us
  unsigned short* qxybf = xspbf + 16777216;                      // 16,777,216 us (qr, then xy)

  float* out_logits = (float*)d_out;
  float* out_embed  = out_logits + (size_t)BB * TT * VV;
  float* out_trace  = out_embed + (size_t)BB * DD;

  // one-time weight transpose-casts (per launch; graph-safe)
  k_tcast<<<dim3(NN / 64, DD / 64, NH), 256, 0, stream>>>(enc,  encT,  DD, NN);
  k_tcast<<<dim3(NN / 64, DD / 64, NH), 256, 0, stream>>>(encv, encvT, DD, NN);
  k_tcast<<<dim3(DD / 64, NN / 64, NH), 256, 0, stream>>>(dec,  decT,  NN, DD);

  k_embed_ln<<<BB * TT, 256, 0, stream>>>(ids, tbl, x);
  for (int l = 0; l < NLAYER; ++l) {
    k_xcast  <<<dim3(DD / 64, TT / 64, BB), 256, 0, stream>>>(x, xbf, xTbf);
    k_enc    <<<dim3(NN / 64, TT / 64, BH), 256, 0, stream>>>(xbf, encT, xspbf, qxybf);
    k_scores <<<dim3(TT / 64, TT / 64, BH), 256, 0, stream>>>(qxybf, scbf);
    k_ykv    <<<dim3(DD / 64, TT / 64, BH), 256, 0, stream>>>(scbf, xTbf, ykv);
    k_ln_rows<<<BH * TT, 256, 0, stream>>>(ykv, ykvbf);
    k_ysp_xy <<<dim3(NN / 64, TT / 64, BH), 256, 0, stream>>>(ykvbf, encvT, xspbf, qxybf);
    k_ymlp   <<<dim3(DD / 64, TT / 64, BH), 256, 0, stream>>>(qxybf, decT, ym4);
    k_ln2    <<<BB * TT, 256, 0, stream>>>(x, ym4);
  }
  k_trace    <<<(BB * NH * NN) / 256, 256, 0, stream>>>(qxybf, out_trace);
  k_logits   <<<BB * TT, 256, 0, stream>>>(x, lmh, out_logits);
  k_embedding<<<(BB * DD) / 256, 256, 0, stream>>>(x, out_embed);
}

// Round 9
// 1368.539 us; speedup vs baseline: 4.4130x; 1.1433x over previous
//
#include <hip/hip_runtime.h>
#include <hip/hip_bf16.h>

#define TT 512
#define DD 256
#define NH 4
#define NN 4096
#define VV 256
#define NLAYER 6
#define BB 2
#define BH (BB * NH)
#define NPAIR 2048

typedef __attribute__((ext_vector_type(8))) short bf16x8;
typedef __attribute__((ext_vector_type(4))) float f32x4;
typedef __attribute__((ext_vector_type(8))) unsigned short us8;

__device__ __forceinline__ unsigned short f2bf(float f) {
  unsigned int u = __float_as_uint(f);
  return (unsigned short)((u + 0x7FFFu + ((u >> 16) & 1u)) >> 16);
}
__device__ __forceinline__ float bf2f(unsigned short h) {
  return __uint_as_float((unsigned int)h << 16);
}

// ---------------- block-wide sum over 256 threads ----------------
__device__ __forceinline__ float block_sum_256(float v) {
  __shared__ float s[4];
  #pragma unroll
  for (int o = 32; o > 0; o >>= 1) v += __shfl_down(v, o);
  int lane = threadIdx.x & 63, wid = threadIdx.x >> 6;
  if (lane == 0) s[wid] = v;
  __syncthreads();
  float r = s[0] + s[1] + s[2] + s[3];
  __syncthreads();
  return r;
}

// ---- 64x64 MFMA tile (verified R7/R8): C = A(64xK)·B(64xK)^T ----
__device__ __forceinline__ void mfma_tile_bt(const unsigned short* __restrict__ A, int lda,
                                             const unsigned short* __restrict__ B, int ldb,
                                             int K, f32x4 acc[4],
                                             unsigned short As[64][40],
                                             unsigned short Bs[64][40]) {
  const int tid = threadIdx.x;
  const int lane = tid & 63, wave = tid >> 6;
  const int srow = tid >> 2, sk = (tid & 3) << 3;
  const int fm = lane & 15, fq = lane >> 4;
  for (int k0 = 0; k0 < K; k0 += 32) {
    *(us8*)(&As[srow][sk]) = *(const us8*)(A + (size_t)srow * lda + k0 + sk);
    *(us8*)(&Bs[srow][sk]) = *(const us8*)(B + (size_t)srow * ldb + k0 + sk);
    __syncthreads();
    bf16x8 a = *(const bf16x8*)(&As[wave * 16 + fm][fq << 3]);
    #pragma unroll
    for (int nt = 0; nt < 4; ++nt) {
      bf16x8 b = *(const bf16x8*)(&Bs[nt * 16 + fm][fq << 3]);
      acc[nt] = __builtin_amdgcn_mfma_f32_16x16x32_bf16(a, b, acc[nt], 0, 0, 0);
    }
    __syncthreads();
  }
}

// ---- 128x128 MFMA tile: 4 waves, each 64x64 (4x4 accs), BK=32 ----
// Same fragment/LDS conventions as the 64-tile core, scaled up.
// wave w: rows (w>>1)*64.., cols (w&1)*64.. within the 128x128 tile.
__device__ __forceinline__ void mfma_tile128_bt(const unsigned short* __restrict__ A, int lda,
                                                const unsigned short* __restrict__ B, int ldb,
                                                int K, f32x4 acc[4][4],
                                                unsigned short As[128][40],
                                                unsigned short Bs[128][40]) {
  const int tid = threadIdx.x;
  const int lane = tid & 63, wave = tid >> 6;
  const int fm = lane & 15, fq = lane >> 4;
  const int rw = (wave >> 1) << 6, cw = (wave & 1) << 6;
  const int r0s = tid >> 2, c0s = (tid & 3) << 3;  // staging: 2 us8 chunks per matrix
  for (int k0 = 0; k0 < K; k0 += 32) {
    us8 a0 = *(const us8*)(A + (size_t)r0s * lda + k0 + c0s);
    us8 a1 = *(const us8*)(A + (size_t)(r0s + 64) * lda + k0 + c0s);
    us8 b0 = *(const us8*)(B + (size_t)r0s * ldb + k0 + c0s);
    us8 b1 = *(const us8*)(B + (size_t)(r0s + 64) * ldb + k0 + c0s);
    __syncthreads();  // prior iteration's ds_reads complete before overwrite
    *(us8*)(&As[r0s][c0s]) = a0;
    *(us8*)(&As[r0s + 64][c0s]) = a1;
    *(us8*)(&Bs[r0s][c0s]) = b0;
    *(us8*)(&Bs[r0s + 64][c0s]) = b1;
    __syncthreads();
    bf16x8 af[4], bfv[4];
    #pragma unroll
    for (int i = 0; i < 4; ++i) {
      af[i]  = *(const bf16x8*)(&As[rw + i * 16 + fm][fq << 3]);
      bfv[i] = *(const bf16x8*)(&Bs[cw + i * 16 + fm][fq << 3]);
    }
    #pragma unroll
    for (int mi = 0; mi < 4; ++mi)
      #pragma unroll
      for (int ni = 0; ni < 4; ++ni)
        acc[mi][ni] = __builtin_amdgcn_mfma_f32_16x16x32_bf16(af[mi], bfv[ni], acc[mi][ni], 0, 0, 0);
  }
}
// C/D: row = m0 + rw + mi*16 + (lane>>4)*4 + r ; col = n0 + cw + ni*16 + (lane&15)

// ---------------- small kernels ----------------

__global__ __launch_bounds__(256) void k_csinit(float2* __restrict__ cs) {
  int idx = blockIdx.x * 256 + threadIdx.x;
  int t = idx >> 11, p = idx & (NPAIR - 1);
  const float INV2PI = 0.15915494309189535f;
  const float TWOPI = 6.283185307179586f;
  float f = exp2f(-16.0f * (float)(2 * p) / (float)NN) * INV2PI;
  float ph = fmodf((float)t * f, 1.0f) * TWOPI;
  float s, c;
  sincosf(ph, &s, &c);
  cs[idx] = make_float2(c, s);
}

__global__ __launch_bounds__(256) void k_tcast(const float* __restrict__ in,
                                               unsigned short* __restrict__ out,
                                               int R, int C) {
  __shared__ float tile[64][65];
  const size_t zoff = (size_t)blockIdx.z * R * C;
  const int r0 = blockIdx.y * 64, c0 = blockIdx.x * 64;
  const int cl = threadIdx.x & 63, r4 = threadIdx.x >> 6;
  #pragma unroll 4
  for (int i = 0; i < 16; ++i) {
    int rl = r4 * 16 + i;
    tile[rl][cl] = in[zoff + (size_t)(r0 + rl) * C + c0 + cl];
  }
  __syncthreads();
  #pragma unroll 4
  for (int i = 0; i < 16; ++i) {
    int ccl = r4 * 16 + i;
    out[zoff + (size_t)(c0 + ccl) * R + r0 + cl] = f2bf(tile[cl][ccl]);
  }
}

__global__ __launch_bounds__(256) void k_xcast(const float* __restrict__ x,
                                               unsigned short* __restrict__ xbf,
                                               unsigned short* __restrict__ xTbf) {
  __shared__ float tile[64][65];
  const int b = blockIdx.z;
  const float* in = x + (size_t)b * TT * DD;
  unsigned short* oR = xbf + (size_t)b * TT * DD;
  unsigned short* oT = xTbf + (size_t)b * DD * TT;
  const int r0 = blockIdx.y * 64, c0 = blockIdx.x * 64;
  const int cl = threadIdx.x & 63, r4 = threadIdx.x >> 6;
  #pragma unroll 4
  for (int i = 0; i < 16; ++i) {
    int rl = r4 * 16 + i;
    float v = in[(size_t)(r0 + rl) * DD + c0 + cl];
    tile[rl][cl] = v;
    oR[(size_t)(r0 + rl) * DD + c0 + cl] = f2bf(v);
  }
  __syncthreads();
  #pragma unroll 4
  for (int i = 0; i < 16; ++i) {
    int ccl = r4 * 16 + i;
    oT[(size_t)(c0 + ccl) * TT + r0 + cl] = f2bf(tile[cl][ccl]);
  }
}

__global__ __launch_bounds__(256) void k_embed_ln(const int* __restrict__ idw,
                                                  const float* __restrict__ tbl,
                                                  float* __restrict__ x) {
  __shared__ int s_id;
  int row = blockIdx.x, tid = threadIdx.x;
  if (tid == 0) {
    bool is64 = true;
    for (int i = 1; i < 64; i += 2)
      if (idw[i] != 0) { is64 = false; break; }
    s_id = is64 ? idw[2 * row] : idw[row];
  }
  __syncthreads();
  int id = s_id;
  float v = tbl[(size_t)id * DD + tid];
  float mu = block_sum_256(v) * (1.0f / DD);
  float d = v - mu;
  float var = block_sum_256(d * d) * (1.0f / DD);
  x[(size_t)row * DD + tid] = d * rsqrtf(var + 1e-5f);
}

// ---------------- GEMM kernels (128-tile) ----------------

// xsp = bf16(relu(x @ enc[h])); qr = bf16(rope(relu)) via cs table
__global__ __launch_bounds__(256) void k_enc(const unsigned short* __restrict__ xbf,
                                             const unsigned short* __restrict__ encT,
                                             const float2* __restrict__ cs,
                                             unsigned short* __restrict__ xsp,
                                             unsigned short* __restrict__ qr) {
  __shared__ unsigned short As[128][40], Bs[128][40];
  const int bh = blockIdx.z, b = bh >> 2, h = bh & 3;
  const int m0 = blockIdx.y * 128, n0 = blockIdx.x * 128;
  f32x4 acc[4][4] = {};
  mfma_tile128_bt(xbf + (size_t)b * TT * DD + (size_t)m0 * DD, DD,
                  encT + (size_t)h * NN * DD + (size_t)n0 * DD, DD, DD, acc, As, Bs);
  const int lane = threadIdx.x & 63, wave = threadIdx.x >> 6;
  const int fm = lane & 15, fq = lane >> 4;
  const int rw = (wave >> 1) << 6, cw = (wave & 1) << 6;
  const size_t base = (size_t)bh * TT * NN;
  const int odd = fm & 1;
  #pragma unroll
  for (int ni = 0; ni < 4; ++ni) {
    const int n = n0 + cw + ni * 16 + fm;
    #pragma unroll
    for (int mi = 0; mi < 4; ++mi) {
      const int trow = m0 + rw + mi * 16 + (fq << 2);
      #pragma unroll
      for (int r = 0; r < 4; ++r) {
        const int t = trow + r;
        float v = fmaxf(acc[mi][ni][r], 0.0f);
        float vp = __shfl_xor(v, 1);
        size_t off = base + (size_t)t * NN + n;
        xsp[off] = f2bf(v);
        float2 c = cs[(size_t)t * NPAIR + (n >> 1)];
        qr[off] = f2bf(v * c.x + (odd ? vp : -vp) * c.y);
      }
    }
  }
}

// sc_bf[t,s] = bf16((s < t) ? qr[t,:]·qr[s,:] : 0)
__global__ __launch_bounds__(256) void k_scores(const unsigned short* __restrict__ qr,
                                                unsigned short* __restrict__ sc) {
  const int bh = blockIdx.z;
  const int m0 = blockIdx.y * 128, n0 = blockIdx.x * 128;
  const int tid = threadIdx.x;
  unsigned short* C = sc + (size_t)bh * TT * TT;
  if (n0 > m0) {  // fully masked tile
    us8 z = {0, 0, 0, 0, 0, 0, 0, 0};
    const int r = tid >> 1, cc = (tid & 1) << 6;
    #pragma unroll
    for (int j = 0; j < 8; ++j)
      *(us8*)(C + (size_t)(m0 + r) * TT + n0 + cc + j * 8) = z;
    return;
  }
  __shared__ unsigned short As[128][40], Bs[128][40];
  const unsigned short* Q = qr + (size_t)bh * TT * NN;
  f32x4 acc[4][4] = {};
  mfma_tile128_bt(Q + (size_t)m0 * NN, NN, Q + (size_t)n0 * NN, NN, NN, acc, As, Bs);
  const int lane = tid & 63, wave = tid >> 6;
  const int fm = lane & 15, fq = lane >> 4;
  const int rw = (wave >> 1) << 6, cw = (wave & 1) << 6;
  #pragma unroll
  for (int ni = 0; ni < 4; ++ni) {
    int s = n0 + cw + ni * 16 + fm;
    #pragma unroll
    for (int mi = 0; mi < 4; ++mi) {
      int trow = m0 + rw + mi * 16 + (fq << 2);
      #pragma unroll
      for (int r = 0; r < 4; ++r) {
        int t = trow + r;
        C[(size_t)t * TT + s] = f2bf((s < t) ? acc[mi][ni][r] : 0.0f);
      }
    }
  }
}

// ykv = sc_bf @ x (pre-LN, f32 out) — 64-tile core
__global__ __launch_bounds__(256) void k_ykv(const unsigned short* __restrict__ sc,
                                             const unsigned short* __restrict__ xTbf,
                                             float* __restrict__ ykv) {
  __shared__ unsigned short As[64][40], Bs[64][40];
  const int bh = blockIdx.z, b = bh >> 2;
  const int m0 = blockIdx.y * 64, n0 = blockIdx.x * 64;
  f32x4 acc[4] = {};
  mfma_tile_bt(sc + (size_t)bh * TT * TT + (size_t)m0 * TT, TT,
               xTbf + (size_t)b * DD * TT + (size_t)n0 * TT, TT, TT, acc, As, Bs);
  const int lane = threadIdx.x & 63, wave = threadIdx.x >> 6;
  const int fm = lane & 15, fq = lane >> 4;
  const int trow = m0 + wave * 16 + (fq << 2);
  float* C = ykv + (size_t)bh * TT * DD;
  #pragma unroll
  for (int nt = 0; nt < 4; ++nt) {
    int d = n0 + nt * 16 + fm;
    #pragma unroll
    for (int r = 0; r < 4; ++r)
      C[(size_t)(trow + r) * DD + d] = acc[nt][r];
  }
}

__global__ __launch_bounds__(256) void k_ln_rows(float* __restrict__ p,
                                                 unsigned short* __restrict__ pbf) {
  int row = blockIdx.x, tid = threadIdx.x;
  float v = p[(size_t)row * DD + tid];
  float mu = block_sum_256(v) * (1.0f / DD);
  float d = v - mu;
  float var = block_sum_256(d * d) * (1.0f / DD);
  float r = d * rsqrtf(var + 1e-5f);
  p[(size_t)row * DD + tid] = r;
  pbf[(size_t)row * DD + tid] = f2bf(r);
}

// xy_bf = xsp_bf * relu(ykv_bf @ encv[h])
__global__ __launch_bounds__(256) void k_ysp_xy(const unsigned short* __restrict__ ykvbf,
                                                const unsigned short* __restrict__ encvT,
                                                const unsigned short* __restrict__ xsp,
                                                unsigned short* __restrict__ xy) {
  __shared__ unsigned short As[128][40], Bs[128][40];
  const int bh = blockIdx.z, h = bh & 3;
  const int m0 = blockIdx.y * 128, n0 = blockIdx.x * 128;
  f32x4 acc[4][4] = {};
  mfma_tile128_bt(ykvbf + (size_t)bh * TT * DD + (size_t)m0 * DD, DD,
                  encvT + (size_t)h * NN * DD + (size_t)n0 * DD, DD, DD, acc, As, Bs);
  const int lane = threadIdx.x & 63, wave = threadIdx.x >> 6;
  const int fm = lane & 15, fq = lane >> 4;
  const int rw = (wave >> 1) << 6, cw = (wave & 1) << 6;
  const size_t base = (size_t)bh * TT * NN;
  #pragma unroll
  for (int ni = 0; ni < 4; ++ni) {
    int n = n0 + cw + ni * 16 + fm;
    #pragma unroll
    for (int mi = 0; mi < 4; ++mi) {
      int trow = m0 + rw + mi * 16 + (fq << 2);
      #pragma unroll
      for (int r = 0; r < 4; ++r) {
        size_t off = base + (size_t)(trow + r) * NN + n;
        xy[off] = f2bf(bf2f(xsp[off]) * fmaxf(acc[mi][ni][r], 0.0f));
      }
    }
  }
}

// ym8[bh*2+ks] = xy_bf[b,h][:, ks*2048 : +2048] @ dec[h] chunk  (K-split 2)
__global__ __launch_bounds__(256) void k_ymlp(const unsigned short* __restrict__ xy,
                                              const unsigned short* __restrict__ decT,
                                              float* __restrict__ ym8) {
  __shared__ unsigned short As[128][40], Bs[128][40];
  const int z = blockIdx.z, bh = z >> 1, ks = z & 1, h = bh & 3;
  const int m0 = blockIdx.y * 128, n0 = blockIdx.x * 128;
  f32x4 acc[4][4] = {};
  mfma_tile128_bt(xy + (size_t)bh * TT * NN + (size_t)m0 * NN + ks * 2048, NN,
                  decT + (size_t)h * DD * NN + (size_t)n0 * NN + ks * 2048, NN,
                  2048, acc, As, Bs);
  const int lane = threadIdx.x & 63, wave = threadIdx.x >> 6;
  const int fm = lane & 15, fq = lane >> 4;
  const int rw = (wave >> 1) << 6, cw = (wave & 1) << 6;
  float* C = ym8 + (size_t)z * TT * DD;
  #pragma unroll
  for (int ni = 0; ni < 4; ++ni) {
    int d = n0 + cw + ni * 16 + fm;
    #pragma unroll
    for (int mi = 0; mi < 4; ++mi) {
      int trow = m0 + rw + mi * 16 + (fq << 2);
      #pragma unroll
      for (int r = 0; r < 4; ++r)
        C[(size_t)(trow + r) * DD + d] = acc[mi][ni][r];
    }
  }
}

// x = LN(x + LN(sum of 8 partials))
__global__ __launch_bounds__(256) void k_ln2(float* __restrict__ x,
                                             const float* __restrict__ ym8) {
  int row = blockIdx.x, tid = threadIdx.x;
  int b = row >> 9, t = row & 511;
  float y = 0.0f;
  #pragma unroll
  for (int p = 0; p < 8; ++p)
    y += ym8[(size_t)(b * 8 + p) * TT * DD + (size_t)t * DD + tid];
  float mu = block_sum_256(y) * (1.0f / DD);
  float d = y - mu;
  float var = block_sum_256(d * d) * (1.0f / DD);
  float ly = d * rsqrtf(var + 1e-5f);
  float xv = x[(size_t)row * DD + tid] + ly;
  float mu2 = block_sum_256(xv) * (1.0f / DD);
  float d2 = xv - mu2;
  float var2 = block_sum_256(d2 * d2) * (1.0f / DD);
  x[(size_t)row * DD + tid] = d2 * rsqrtf(var2 + 1e-5f);
}

__global__ __launch_bounds__(256) void k_trace(const unsigned short* __restrict__ xy,
                                               float* __restrict__ out) {
  int idx = blockIdx.x * 256 + threadIdx.x;
  int b = idx >> 14, c = idx & 16383;
  int h = c >> 12, n = c & 4095;
  size_t base = (size_t)(b * 4 + h) * TT * NN + n;
  float s = 0.0f;
  for (int t = 0; t < TT; ++t) s += bf2f(xy[base + (size_t)t * NN]);
  out[idx] = s * (1.0f / TT);
}

__global__ __launch_bounds__(256) void k_logits(const float* __restrict__ x,
                                                const float* __restrict__ W,
                                                float* __restrict__ out) {
  __shared__ float xs[DD];
  int row = blockIdx.x, tid = threadIdx.x;
  xs[tid] = x[(size_t)row * DD + tid];
  __syncthreads();
  float s = 0.0f;
  #pragma unroll 8
  for (int d = 0; d < DD; ++d) s = fmaf(xs[d], W[(size_t)d * VV + tid], s);
  out[(size_t)row * VV + tid] = s;
}

__global__ __launch_bounds__(256) void k_embedding(const float* __restrict__ x,
                                                   float* __restrict__ out) {
  int idx = blockIdx.x * 256 + threadIdx.x;
  int b = idx >> 8, d = idx & 255;
  float s = 0.0f;
  for (int t = 0; t < TT; ++t) s += x[(size_t)(b * TT + t) * DD + d];
  out[idx] = s * (1.0f / TT);
}

extern "C" void kernel_launch(void* const* d_in, const int* in_sizes, int n_in,
                              void* d_out, int out_size, void* d_ws, size_t ws_size,
                              hipStream_t stream) {
  const int*   ids  = (const int*)d_in[0];
  const float* tbl  = (const float*)d_in[1];
  const float* enc  = (const float*)d_in[2];
  const float* encv = (const float*)d_in[3];
  const float* dec  = (const float*)d_in[4];
  const float* lmh  = (const float*)d_in[5];

  // workspace layout (float units), ~122 MiB total
  float* ws   = (float*)d_ws;
  float* x    = ws;                                              //   262,144 f
  unsigned short* scbf  = (unsigned short*)(x + 262144);         // 2,097,152 us
  float* ykv  = (float*)(scbf + 2097152);                        // 1,048,576 f
  unsigned short* ykvbf = (unsigned short*)(ykv + 1048576);      // 1,048,576 us
  float* ym8  = (float*)(ykvbf + 1048576);                       // 2,097,152 f
  unsigned short* xbf   = (unsigned short*)(ym8 + 2097152);      //   262,144 us
  unsigned short* xTbf  = xbf + 262144;                          //   262,144 us
  unsigned short* encT  = xTbf + 262144;                         // 4,194,304 us
  unsigned short* encvT = encT + 4194304;                        // 4,194,304 us
  unsigned short* decT  = encvT + 4194304;                       // 4,194,304 us
  unsigned short* xspbf = decT + 4194304;                        // 16,777,216 us
  unsigned short* qxybf = xspbf + 16777216;                      // 16,777,216 us
  float2* cs  = (float2*)(qxybf + 16777216);                     // 1,048,576 float2

  float* out_logits = (float*)d_out;
  float* out_embed  = out_logits + (size_t)BB * TT * VV;
  float* out_trace  = out_embed + (size_t)BB * DD;

  k_csinit<<<(TT * NPAIR) / 256, 256, 0, stream>>>(cs);
  k_tcast<<<dim3(NN / 64, DD / 64, NH), 256, 0, stream>>>(enc,  encT,  DD, NN);
  k_tcast<<<dim3(NN / 64, DD / 64, NH), 256, 0, stream>>>(encv, encvT, DD, NN);
  k_tcast<<<dim3(DD / 64, NN / 64, NH), 256, 0, stream>>>(dec,  decT,  NN, DD);

  k_embed_ln<<<BB * TT, 256, 0, stream>>>(ids, tbl, x);
  for (int l = 0; l < NLAYER; ++l) {
    k_xcast  <<<dim3(DD / 64, TT / 64, BB), 256, 0, stream>>>(x, xbf, xTbf);
    k_enc    <<<dim3(NN / 128, TT / 128, BH), 256, 0, stream>>>(xbf, encT, cs, xspbf, qxybf);
    k_scores <<<dim3(TT / 128, TT / 128, BH), 256, 0, stream>>>(qxybf, scbf);
    k_ykv    <<<dim3(DD / 64, TT / 64, BH), 256, 0, stream>>>(scbf, xTbf, ykv);
    k_ln_rows<<<BH * TT, 256, 0, stream>>>(ykv, ykvbf);
    k_ysp_xy <<<dim3(NN / 128, TT / 128, BH), 256, 0, stream>>>(ykvbf, encvT, xspbf, qxybf);
    k_ymlp   <<<dim3(DD / 128, TT / 128, BH * 2), 256, 0, stream>>>(qxybf, decT, ym8);
    k_ln2    <<<BB * TT, 256, 0, stream>>>(x, ym8);
  }
  k_trace    <<<(BB * NH * NN) / 256, 256, 0, stream>>>(qxybf, out_trace);
  k_logits   <<<BB * TT, 256, 0, stream>>>(x, lmh, out_logits);
  k_embedding<<<(BB * DD) / 256, 256, 0, stream>>>(x, out_embed);
}

// Round 10
// 1133.761 us; speedup vs baseline: 5.3268x; 1.2071x over previous
//
#include <hip/hip_runtime.h>
#include <hip/hip_bf16.h>

#define TT 512
#define DD 256
#define NH 4
#define NN 4096
#define VV 256
#define NLAYER 6
#define BB 2
#define BH (BB * NH)
#define NPAIR 2048

typedef __attribute__((ext_vector_type(8))) short bf16x8;
typedef __attribute__((ext_vector_type(4))) float f32x4;
typedef __attribute__((ext_vector_type(8))) unsigned short us8;

__device__ __forceinline__ unsigned short f2bf(float f) {
  unsigned int u = __float_as_uint(f);
  return (unsigned short)((u + 0x7FFFu + ((u >> 16) & 1u)) >> 16);
}
__device__ __forceinline__ float bf2f(unsigned short h) {
  return __uint_as_float((unsigned int)h << 16);
}

// ---------------- block-wide sum over 256 threads ----------------
__device__ __forceinline__ float block_sum_256(float v) {
  __shared__ float s[4];
  #pragma unroll
  for (int o = 32; o > 0; o >>= 1) v += __shfl_down(v, o);
  int lane = threadIdx.x & 63, wid = threadIdx.x >> 6;
  if (lane == 0) s[wid] = v;
  __syncthreads();
  float r = s[0] + s[1] + s[2] + s[3];
  __syncthreads();
  return r;
}

// ---- 64x64 MFMA tile (verified R7/R8): C = A(64xK)·B(64xK)^T ----
__device__ __forceinline__ void mfma_tile_bt(const unsigned short* __restrict__ A, int lda,
                                             const unsigned short* __restrict__ B, int ldb,
                                             int K, f32x4 acc[4],
                                             unsigned short As[64][40],
                                             unsigned short Bs[64][40]) {
  const int tid = threadIdx.x;
  const int lane = tid & 63, wave = tid >> 6;
  const int srow = tid >> 2, sk = (tid & 3) << 3;
  const int fm = lane & 15, fq = lane >> 4;
  for (int k0 = 0; k0 < K; k0 += 32) {
    *(us8*)(&As[srow][sk]) = *(const us8*)(A + (size_t)srow * lda + k0 + sk);
    *(us8*)(&Bs[srow][sk]) = *(const us8*)(B + (size_t)srow * ldb + k0 + sk);
    __syncthreads();
    bf16x8 a = *(const bf16x8*)(&As[wave * 16 + fm][fq << 3]);
    #pragma unroll
    for (int nt = 0; nt < 4; ++nt) {
      bf16x8 b = *(const bf16x8*)(&Bs[nt * 16 + fm][fq << 3]);
      acc[nt] = __builtin_amdgcn_mfma_f32_16x16x32_bf16(a, b, acc[nt], 0, 0, 0);
    }
    __syncthreads();
  }
}

// ---- 128x128 MFMA tile: 4 waves, each 64x64 (4x4 accs), BK=32 ----
__device__ __forceinline__ void mfma_tile128_bt(const unsigned short* __restrict__ A, int lda,
                                                const unsigned short* __restrict__ B, int ldb,
                                                int K, f32x4 acc[4][4],
                                                unsigned short As[128][40],
                                                unsigned short Bs[128][40]) {
  const int tid = threadIdx.x;
  const int lane = tid & 63, wave = tid >> 6;
  const int fm = lane & 15, fq = lane >> 4;
  const int rw = (wave >> 1) << 6, cw = (wave & 1) << 6;
  const int r0s = tid >> 2, c0s = (tid & 3) << 3;
  for (int k0 = 0; k0 < K; k0 += 32) {
    us8 a0 = *(const us8*)(A + (size_t)r0s * lda + k0 + c0s);
    us8 a1 = *(const us8*)(A + (size_t)(r0s + 64) * lda + k0 + c0s);
    us8 b0 = *(const us8*)(B + (size_t)r0s * ldb + k0 + c0s);
    us8 b1 = *(const us8*)(B + (size_t)(r0s + 64) * ldb + k0 + c0s);
    __syncthreads();
    *(us8*)(&As[r0s][c0s]) = a0;
    *(us8*)(&As[r0s + 64][c0s]) = a1;
    *(us8*)(&Bs[r0s][c0s]) = b0;
    *(us8*)(&Bs[r0s + 64][c0s]) = b1;
    __syncthreads();
    bf16x8 af[4], bfv[4];
    #pragma unroll
    for (int i = 0; i < 4; ++i) {
      af[i]  = *(const bf16x8*)(&As[rw + i * 16 + fm][fq << 3]);
      bfv[i] = *(const bf16x8*)(&Bs[cw + i * 16 + fm][fq << 3]);
    }
    #pragma unroll
    for (int mi = 0; mi < 4; ++mi)
      #pragma unroll
      for (int ni = 0; ni < 4; ++ni)
        acc[mi][ni] = __builtin_amdgcn_mfma_f32_16x16x32_bf16(af[mi], bfv[ni], acc[mi][ni], 0, 0, 0);
  }
}
// C/D: row = m0 + rw + mi*16 + (lane>>4)*4 + r ; col = n0 + cw + ni*16 + (lane&15)

// ---------------- small kernels ----------------

__global__ __launch_bounds__(256) void k_csinit(float2* __restrict__ cs) {
  int idx = blockIdx.x * 256 + threadIdx.x;
  int t = idx >> 11, p = idx & (NPAIR - 1);
  const float INV2PI = 0.15915494309189535f;
  const float TWOPI = 6.283185307179586f;
  float f = exp2f(-16.0f * (float)(2 * p) / (float)NN) * INV2PI;
  float ph = fmodf((float)t * f, 1.0f) * TWOPI;
  float s, c;
  sincosf(ph, &s, &c);
  cs[idx] = make_float2(c, s);
}

__global__ __launch_bounds__(256) void k_tcast(const float* __restrict__ in,
                                               unsigned short* __restrict__ out,
                                               int R, int C) {
  __shared__ float tile[64][65];
  const size_t zoff = (size_t)blockIdx.z * R * C;
  const int r0 = blockIdx.y * 64, c0 = blockIdx.x * 64;
  const int cl = threadIdx.x & 63, r4 = threadIdx.x >> 6;
  #pragma unroll 4
  for (int i = 0; i < 16; ++i) {
    int rl = r4 * 16 + i;
    tile[rl][cl] = in[zoff + (size_t)(r0 + rl) * C + c0 + cl];
  }
  __syncthreads();
  #pragma unroll 4
  for (int i = 0; i < 16; ++i) {
    int ccl = r4 * 16 + i;
    out[zoff + (size_t)(c0 + ccl) * R + r0 + cl] = f2bf(tile[cl][ccl]);
  }
}

// x[b,t,:] = LN(embed[ids]); emits f32 x, bf16 xbf, bf16 xT
__global__ __launch_bounds__(256) void k_embed_ln(const int* __restrict__ idw,
                                                  const float* __restrict__ tbl,
                                                  float* __restrict__ x,
                                                  unsigned short* __restrict__ xbf,
                                                  unsigned short* __restrict__ xTbf) {
  __shared__ int s_id;
  int row = blockIdx.x, tid = threadIdx.x;
  if (tid == 0) {
    bool is64 = true;
    for (int i = 1; i < 64; i += 2)
      if (idw[i] != 0) { is64 = false; break; }
    s_id = is64 ? idw[2 * row] : idw[row];
  }
  __syncthreads();
  int id = s_id;
  float v = tbl[(size_t)id * DD + tid];
  float mu = block_sum_256(v) * (1.0f / DD);
  float d = v - mu;
  float var = block_sum_256(d * d) * (1.0f / DD);
  float r = d * rsqrtf(var + 1e-5f);
  x[(size_t)row * DD + tid] = r;
  unsigned short rb = f2bf(r);
  xbf[(size_t)row * DD + tid] = rb;
  int b = row >> 9, t = row & 511;
  xTbf[((size_t)b * DD + tid) * TT + t] = rb;
}

// ---------------- GEMM kernels ----------------

// xsp = bf16(relu(x @ enc[h])); qr = bf16(rope(relu)) via cs table
__global__ __launch_bounds__(256) void k_enc(const unsigned short* __restrict__ xbf,
                                             const unsigned short* __restrict__ encT,
                                             const float2* __restrict__ cs,
                                             unsigned short* __restrict__ xsp,
                                             unsigned short* __restrict__ qr) {
  __shared__ unsigned short As[128][40], Bs[128][40];
  const int bh = blockIdx.z, b = bh >> 2, h = bh & 3;
  const int m0 = blockIdx.y * 128, n0 = blockIdx.x * 128;
  f32x4 acc[4][4] = {};
  mfma_tile128_bt(xbf + (size_t)b * TT * DD + (size_t)m0 * DD, DD,
                  encT + (size_t)h * NN * DD + (size_t)n0 * DD, DD, DD, acc, As, Bs);
  const int lane = threadIdx.x & 63, wave = threadIdx.x >> 6;
  const int fm = lane & 15, fq = lane >> 4;
  const int rw = (wave >> 1) << 6, cw = (wave & 1) << 6;
  const size_t base = (size_t)bh * TT * NN;
  const int odd = fm & 1;
  #pragma unroll
  for (int ni = 0; ni < 4; ++ni) {
    const int n = n0 + cw + ni * 16 + fm;
    #pragma unroll
    for (int mi = 0; mi < 4; ++mi) {
      const int trow = m0 + rw + mi * 16 + (fq << 2);
      #pragma unroll
      for (int r = 0; r < 4; ++r) {
        const int t = trow + r;
        float v = fmaxf(acc[mi][ni][r], 0.0f);
        float vp = __shfl_xor(v, 1);
        size_t off = base + (size_t)t * NN + n;
        xsp[off] = f2bf(v);
        float2 c = cs[(size_t)t * NPAIR + (n >> 1)];
        qr[off] = f2bf(v * c.x + (odd ? vp : -vp) * c.y);
      }
    }
  }
}

// scores partials: scp[bh*4+kc] = qr[:,kc*1024:+1024] · qr^T chunk (f32)
__global__ __launch_bounds__(256) void k_scores_part(const unsigned short* __restrict__ qr,
                                                     float* __restrict__ scp) {
  const int z = blockIdx.z, bh = z >> 2, kc = z & 3;
  const int m0 = blockIdx.y * 128, n0 = blockIdx.x * 128;
  if (n0 > m0) return;  // upper tiles handled by k_scred
  __shared__ unsigned short As[128][40], Bs[128][40];
  const unsigned short* Q = qr + (size_t)bh * TT * NN + kc * 1024;
  f32x4 acc[4][4] = {};
  mfma_tile128_bt(Q + (size_t)m0 * NN, NN, Q + (size_t)n0 * NN, NN, 1024, acc, As, Bs);
  const int lane = threadIdx.x & 63, wave = threadIdx.x >> 6;
  const int fm = lane & 15, fq = lane >> 4;
  const int rw = (wave >> 1) << 6, cw = (wave & 1) << 6;
  float* C = scp + (size_t)z * TT * TT;
  #pragma unroll
  for (int ni = 0; ni < 4; ++ni) {
    int s = n0 + cw + ni * 16 + fm;
    #pragma unroll
    for (int mi = 0; mi < 4; ++mi) {
      int trow = m0 + rw + mi * 16 + (fq << 2);
      #pragma unroll
      for (int r = 0; r < 4; ++r)
        C[(size_t)(trow + r) * TT + s] = acc[mi][ni][r];
    }
  }
}

// sc_bf[t,s] = bf16((s<t) ? sum_kc scp : 0)
__global__ __launch_bounds__(256) void k_scred(const float* __restrict__ scp,
                                               unsigned short* __restrict__ sc) {
  int idx = blockIdx.x * 256 + threadIdx.x;       // bh*T*T + t*T + s
  int bh = idx >> 18, rem = idx & (TT * TT - 1);
  int t = rem >> 9, s = rem & 511;
  float v = 0.0f;
  if (s < t) {
    size_t base = ((size_t)bh * 4) * TT * TT + rem;
    v = scp[base] + scp[base + (size_t)TT * TT] +
        scp[base + (size_t)2 * TT * TT] + scp[base + (size_t)3 * TT * TT];
  }
  sc[idx] = f2bf(v);
}

// ykv = sc_bf @ x (pre-LN, f32 out) — 64-tile core
__global__ __launch_bounds__(256) void k_ykv(const unsigned short* __restrict__ sc,
                                             const unsigned short* __restrict__ xTbf,
                                             float* __restrict__ ykv) {
  __shared__ unsigned short As[64][40], Bs[64][40];
  const int bh = blockIdx.z, b = bh >> 2;
  const int m0 = blockIdx.y * 64, n0 = blockIdx.x * 64;
  f32x4 acc[4] = {};
  mfma_tile_bt(sc + (size_t)bh * TT * TT + (size_t)m0 * TT, TT,
               xTbf + (size_t)b * DD * TT + (size_t)n0 * TT, TT, TT, acc, As, Bs);
  const int lane = threadIdx.x & 63, wave = threadIdx.x >> 6;
  const int fm = lane & 15, fq = lane >> 4;
  const int trow = m0 + wave * 16 + (fq << 2);
  float* C = ykv + (size_t)bh * TT * DD;
  #pragma unroll
  for (int nt = 0; nt < 4; ++nt) {
    int d = n0 + nt * 16 + fm;
    #pragma unroll
    for (int r = 0; r < 4; ++r)
      C[(size_t)(trow + r) * DD + d] = acc[nt][r];
  }
}

__global__ __launch_bounds__(256) void k_ln_rows(float* __restrict__ p,
                                                 unsigned short* __restrict__ pbf) {
  int row = blockIdx.x, tid = threadIdx.x;
  float v = p[(size_t)row * DD + tid];
  float mu = block_sum_256(v) * (1.0f / DD);
  float d = v - mu;
  float var = block_sum_256(d * d) * (1.0f / DD);
  float r = d * rsqrtf(var + 1e-5f);
  p[(size_t)row * DD + tid] = r;
  pbf[(size_t)row * DD + tid] = f2bf(r);
}

// xy_bf = xsp_bf * relu(ykv_bf @ encv[h])
__global__ __launch_bounds__(256) void k_ysp_xy(const unsigned short* __restrict__ ykvbf,
                                                const unsigned short* __restrict__ encvT,
                                                const unsigned short* __restrict__ xsp,
                                                unsigned short* __restrict__ xy) {
  __shared__ unsigned short As[128][40], Bs[128][40];
  const int bh = blockIdx.z, h = bh & 3;
  const int m0 = blockIdx.y * 128, n0 = blockIdx.x * 128;
  f32x4 acc[4][4] = {};
  mfma_tile128_bt(ykvbf + (size_t)bh * TT * DD + (size_t)m0 * DD, DD,
                  encvT + (size_t)h * NN * DD + (size_t)n0 * DD, DD, DD, acc, As, Bs);
  const int lane = threadIdx.x & 63, wave = threadIdx.x >> 6;
  const int fm = lane & 15, fq = lane >> 4;
  const int rw = (wave >> 1) << 6, cw = (wave & 1) << 6;
  const size_t base = (size_t)bh * TT * NN;
  #pragma unroll
  for (int ni = 0; ni < 4; ++ni) {
    int n = n0 + cw + ni * 16 + fm;
    #pragma unroll
    for (int mi = 0; mi < 4; ++mi) {
      int trow = m0 + rw + mi * 16 + (fq << 2);
      #pragma unroll
      for (int r = 0; r < 4; ++r) {
        size_t off = base + (size_t)(trow + r) * NN + n;
        xy[off] = f2bf(bf2f(xsp[off]) * fmaxf(acc[mi][ni][r], 0.0f));
      }
    }
  }
}

// ym8[bh*2+ks] = xy_bf chunk @ dec[h] chunk  (K-split 2)
__global__ __launch_bounds__(256) void k_ymlp(const unsigned short* __restrict__ xy,
                                              const unsigned short* __restrict__ decT,
                                              float* __restrict__ ym8) {
  __shared__ unsigned short As[128][40], Bs[128][40];
  const int z = blockIdx.z, bh = z >> 1, ks = z & 1, h = bh & 3;
  const int m0 = blockIdx.y * 128, n0 = blockIdx.x * 128;
  f32x4 acc[4][4] = {};
  mfma_tile128_bt(xy + (size_t)bh * TT * NN + (size_t)m0 * NN + ks * 2048, NN,
                  decT + (size_t)h * DD * NN + (size_t)n0 * NN + ks * 2048, NN,
                  2048, acc, As, Bs);
  const int lane = threadIdx.x & 63, wave = threadIdx.x >> 6;
  const int fm = lane & 15, fq = lane >> 4;
  const int rw = (wave >> 1) << 6, cw = (wave & 1) << 6;
  float* C = ym8 + (size_t)z * TT * DD;
  #pragma unroll
  for (int ni = 0; ni < 4; ++ni) {
    int d = n0 + cw + ni * 16 + fm;
    #pragma unroll
    for (int mi = 0; mi < 4; ++mi) {
      int trow = m0 + rw + mi * 16 + (fq << 2);
      #pragma unroll
      for (int r = 0; r < 4; ++r)
        C[(size_t)(trow + r) * DD + d] = acc[mi][ni][r];
    }
  }
}

// x = LN(x + LN(sum of 8 partials)); emits f32 x, bf16 xbf, bf16 xT
__global__ __launch_bounds__(256) void k_ln2(float* __restrict__ x,
                                             const float* __restrict__ ym8,
                                             unsigned short* __restrict__ xbf,
                                             unsigned short* __restrict__ xTbf) {
  int row = blockIdx.x, tid = threadIdx.x;
  int b = row >> 9, t = row & 511;
  float y = 0.0f;
  #pragma unroll
  for (int p = 0; p < 8; ++p)
    y += ym8[(size_t)(b * 8 + p) * TT * DD + (size_t)t * DD + tid];
  float mu = block_sum_256(y) * (1.0f / DD);
  float d = y - mu;
  float var = block_sum_256(d * d) * (1.0f / DD);
  float ly = d * rsqrtf(var + 1e-5f);
  float xv = x[(size_t)row * DD + tid] + ly;
  float mu2 = block_sum_256(xv) * (1.0f / DD);
  float d2 = xv - mu2;
  float var2 = block_sum_256(d2 * d2) * (1.0f / DD);
  float r = d2 * rsqrtf(var2 + 1e-5f);
  x[(size_t)row * DD + tid] = r;
  unsigned short rb = f2bf(r);
  xbf[(size_t)row * DD + tid] = rb;
  xTbf[((size_t)b * DD + tid) * TT + t] = rb;
}

__global__ __launch_bounds__(256) void k_trace(const unsigned short* __restrict__ xy,
                                               float* __restrict__ out) {
  int idx = blockIdx.x * 256 + threadIdx.x;
  int b = idx >> 14, c = idx & 16383;
  int h = c >> 12, n = c & 4095;
  size_t base = (size_t)(b * 4 + h) * TT * NN + n;
  float s = 0.0f;
  for (int t = 0; t < TT; ++t) s += bf2f(xy[base + (size_t)t * NN]);
  out[idx] = s * (1.0f / TT);
}

__global__ __launch_bounds__(256) void k_logits(const float* __restrict__ x,
                                                const float* __restrict__ W,
                                                float* __restrict__ out) {
  __shared__ float xs[DD];
  int row = blockIdx.x, tid = threadIdx.x;
  xs[tid] = x[(size_t)row * DD + tid];
  __syncthreads();
  float s = 0.0f;
  #pragma unroll 8
  for (int d = 0; d < DD; ++d) s = fmaf(xs[d], W[(size_t)d * VV + tid], s);
  out[(size_t)row * VV + tid] = s;
}

__global__ __launch_bounds__(256) void k_embedding(const float* __restrict__ x,
                                                   float* __restrict__ out) {
  int idx = blockIdx.x * 256 + threadIdx.x;
  int b = idx >> 8, d = idx & 255;
  float s = 0.0f;
  for (int t = 0; t < TT; ++t) s += x[(size_t)(b * TT + t) * DD + d];
  out[idx] = s * (1.0f / TT);
}

extern "C" void kernel_launch(void* const* d_in, const int* in_sizes, int n_in,
                              void* d_out, int out_size, void* d_ws, size_t ws_size,
                              hipStream_t stream) {
  const int*   ids  = (const int*)d_in[0];
  const float* tbl  = (const float*)d_in[1];
  const float* enc  = (const float*)d_in[2];
  const float* encv = (const float*)d_in[3];
  const float* dec  = (const float*)d_in[4];
  const float* lmh  = (const float*)d_in[5];

  // workspace layout (float units), ~155 MiB total (R3 proved >=195 MiB usable)
  float* ws   = (float*)d_ws;
  float* x    = ws;                                              //   262,144 f
  unsigned short* scbf  = (unsigned short*)(x + 262144);         // 2,097,152 us
  float* ykv  = (float*)(scbf + 2097152);                        // 1,048,576 f
  unsigned short* ykvbf = (unsigned short*)(ykv + 1048576);      // 1,048,576 us
  float* ym8  = (float*)(ykvbf + 1048576);                       // 2,097,152 f
  unsigned short* xbf   = (unsigned short*)(ym8 + 2097152);      //   262,144 us
  unsigned short* xTbf  = xbf + 262144;                          //   262,144 us
  unsigned short* encT  = xTbf + 262144;                         // 4,194,304 us
  unsigned short* encvT = encT + 4194304;                        // 4,194,304 us
  unsigned short* decT  = encvT + 4194304;                       // 4,194,304 us
  unsigned short* xspbf = decT + 4194304;                        // 16,777,216 us
  unsigned short* qxybf = xspbf + 16777216;                      // 16,777,216 us
  float2* cs  = (float2*)(qxybf + 16777216);                     // 1,048,576 float2
  float* scp  = (float*)(cs + 1048576);                          // 8,388,608 f (32 MiB)

  float* out_logits = (float*)d_out;
  float* out_embed  = out_logits + (size_t)BB * TT * VV;
  float* out_trace  = out_embed + (size_t)BB * DD;

  k_csinit<<<(TT * NPAIR) / 256, 256, 0, stream>>>(cs);
  k_tcast<<<dim3(NN / 64, DD / 64, NH), 256, 0, stream>>>(enc,  encT,  DD, NN);
  k_tcast<<<dim3(NN / 64, DD / 64, NH), 256, 0, stream>>>(encv, encvT, DD, NN);
  k_tcast<<<dim3(DD / 64, NN / 64, NH), 256, 0, stream>>>(dec,  decT,  NN, DD);

  k_embed_ln<<<BB * TT, 256, 0, stream>>>(ids, tbl, x, xbf, xTbf);
  for (int l = 0; l < NLAYER; ++l) {
    k_enc        <<<dim3(NN / 128, TT / 128, BH), 256, 0, stream>>>(xbf, encT, cs, xspbf, qxybf);
    k_scores_part<<<dim3(TT / 128, TT / 128, BH * 4), 256, 0, stream>>>(qxybf, scp);
    k_scred      <<<(BH * TT * TT) / 256, 256, 0, stream>>>(scp, scbf);
    k_ykv        <<<dim3(DD / 64, TT / 64, BH), 256, 0, stream>>>(scbf, xTbf, ykv);
    k_ln_rows    <<<BH * TT, 256, 0, stream>>>(ykv, ykvbf);
    k_ysp_xy     <<<dim3(NN / 128, TT / 128, BH), 256, 0, stream>>>(ykvbf, encvT, xspbf, qxybf);
    k_ymlp       <<<dim3(DD / 128, TT / 128, BH * 2), 256, 0, stream>>>(qxybf, decT, ym8);
    k_ln2        <<<BB * TT, 256, 0, stream>>>(x, ym8, xbf, xTbf);
  }
  k_trace    <<<(BB * NH * NN) / 256, 256, 0, stream>>>(qxybf, out_trace);
  k_logits   <<<BB * TT, 256, 0, stream>>>(x, lmh, out_logits);
  k_embedding<<<(BB * DD) / 256, 256, 0, stream>>>(x, out_embed);
}

// Round 11
// 1081.369 us; speedup vs baseline: 5.5849x; 1.0484x over previous
//
#include <hip/hip_runtime.h>
#include <hip/hip_bf16.h>

#define TT 512
#define DD 256
#define NH 4
#define NN 4096
#define VV 256
#define NLAYER 6
#define BB 2
#define BH (BB * NH)
#define NPAIR 2048

typedef __attribute__((ext_vector_type(8))) short bf16x8;
typedef __attribute__((ext_vector_type(4))) float f32x4;
typedef __attribute__((ext_vector_type(8))) unsigned short us8;

__device__ __forceinline__ unsigned short f2bf(float f) {
  unsigned int u = __float_as_uint(f);
  return (unsigned short)((u + 0x7FFFu + ((u >> 16) & 1u)) >> 16);
}
__device__ __forceinline__ float bf2f(unsigned short h) {
  return __uint_as_float((unsigned int)h << 16);
}

// ---------------- block-wide sum over 256 threads ----------------
__device__ __forceinline__ float block_sum_256(float v) {
  __shared__ float s[4];
  #pragma unroll
  for (int o = 32; o > 0; o >>= 1) v += __shfl_down(v, o);
  int lane = threadIdx.x & 63, wid = threadIdx.x >> 6;
  if (lane == 0) s[wid] = v;
  __syncthreads();
  float r = s[0] + s[1] + s[2] + s[3];
  __syncthreads();
  return r;
}

// ---- 128x128 MFMA tile main loop (verified R9/R10) ----
__device__ __forceinline__ void mfma_tile128_bt(const unsigned short* __restrict__ A, int lda,
                                                const unsigned short* __restrict__ B, int ldb,
                                                int K, f32x4 acc[4][4],
                                                unsigned short (*As)[40],
                                                unsigned short (*Bs)[40]) {
  const int tid = threadIdx.x;
  const int lane = tid & 63, wave = tid >> 6;
  const int fm = lane & 15, fq = lane >> 4;
  const int rw = (wave >> 1) << 6, cw = (wave & 1) << 6;
  const int r0s = tid >> 2, c0s = (tid & 3) << 3;
  for (int k0 = 0; k0 < K; k0 += 32) {
    us8 a0 = *(const us8*)(A + (size_t)r0s * lda + k0 + c0s);
    us8 a1 = *(const us8*)(A + (size_t)(r0s + 64) * lda + k0 + c0s);
    us8 b0 = *(const us8*)(B + (size_t)r0s * ldb + k0 + c0s);
    us8 b1 = *(const us8*)(B + (size_t)(r0s + 64) * ldb + k0 + c0s);
    __syncthreads();
    *(us8*)(&As[r0s][c0s]) = a0;
    *(us8*)(&As[r0s + 64][c0s]) = a1;
    *(us8*)(&Bs[r0s][c0s]) = b0;
    *(us8*)(&Bs[r0s + 64][c0s]) = b1;
    __syncthreads();
    bf16x8 af[4], bfv[4];
    #pragma unroll
    for (int i = 0; i < 4; ++i) {
      af[i]  = *(const bf16x8*)(&As[rw + i * 16 + fm][fq << 3]);
      bfv[i] = *(const bf16x8*)(&Bs[cw + i * 16 + fm][fq << 3]);
    }
    #pragma unroll
    for (int mi = 0; mi < 4; ++mi)
      #pragma unroll
      for (int ni = 0; ni < 4; ++ni)
        acc[mi][ni] = __builtin_amdgcn_mfma_f32_16x16x32_bf16(af[mi], bfv[ni], acc[mi][ni], 0, 0, 0);
  }
}
// C/D: row = m0 + rw + mi*16 + (lane>>4)*4 + r ; col = n0 + cw + ni*16 + (lane&15)

// ---------------- small kernels ----------------

__global__ __launch_bounds__(256) void k_csinit(float2* __restrict__ cs) {
  int idx = blockIdx.x * 256 + threadIdx.x;
  int t = idx >> 11, p = idx & (NPAIR - 1);
  const float INV2PI = 0.15915494309189535f;
  const float TWOPI = 6.283185307179586f;
  float f = exp2f(-16.0f * (float)(2 * p) / (float)NN) * INV2PI;
  float ph = fmodf((float)t * f, 1.0f) * TWOPI;
  float s, c;
  sincosf(ph, &s, &c);
  cs[idx] = make_float2(c, s);
}

__global__ __launch_bounds__(256) void k_tcast(const float* __restrict__ in,
                                               unsigned short* __restrict__ out,
                                               int R, int C) {
  __shared__ float tile[64][65];
  const size_t zoff = (size_t)blockIdx.z * R * C;
  const int r0 = blockIdx.y * 64, c0 = blockIdx.x * 64;
  const int cl = threadIdx.x & 63, r4 = threadIdx.x >> 6;
  #pragma unroll 4
  for (int i = 0; i < 16; ++i) {
    int rl = r4 * 16 + i;
    tile[rl][cl] = in[zoff + (size_t)(r0 + rl) * C + c0 + cl];
  }
  __syncthreads();
  #pragma unroll 4
  for (int i = 0; i < 16; ++i) {
    int ccl = r4 * 16 + i;
    out[zoff + (size_t)(c0 + ccl) * R + r0 + cl] = f2bf(tile[cl][ccl]);
  }
}

// x[b,t,:] = LN(embed[ids]); emits f32 x, bf16 xbf, bf16 xT
__global__ __launch_bounds__(256) void k_embed_ln(const int* __restrict__ idw,
                                                  const float* __restrict__ tbl,
                                                  float* __restrict__ x,
                                                  unsigned short* __restrict__ xbf,
                                                  unsigned short* __restrict__ xTbf) {
  __shared__ int s_id;
  int row = blockIdx.x, tid = threadIdx.x;
  if (tid == 0) {
    bool is64 = true;
    for (int i = 1; i < 64; i += 2)
      if (idw[i] != 0) { is64 = false; break; }
    s_id = is64 ? idw[2 * row] : idw[row];
  }
  __syncthreads();
  int id = s_id;
  float v = tbl[(size_t)id * DD + tid];
  float mu = block_sum_256(v) * (1.0f / DD);
  float d = v - mu;
  float var = block_sum_256(d * d) * (1.0f / DD);
  float r = d * rsqrtf(var + 1e-5f);
  x[(size_t)row * DD + tid] = r;
  unsigned short rb = f2bf(r);
  xbf[(size_t)row * DD + tid] = rb;
  int b = row >> 9, t = row & 511;
  xTbf[((size_t)b * DD + tid) * TT + t] = rb;
}

// ---------------- GEMM kernels ----------------

// xsp = bf16(relu(x @ enc[h])); qr = bf16(rope(relu)) — LDS-transposed epilogue
__global__ __launch_bounds__(256) void k_enc(const unsigned short* __restrict__ xbf,
                                             const unsigned short* __restrict__ encT,
                                             const float2* __restrict__ cs,
                                             unsigned short* __restrict__ xsp,
                                             unsigned short* __restrict__ qr) {
  __shared__ float smemf[5120];  // 20480 B: As/Bs in main loop, f32 scratch in epilogue
  unsigned short (*As)[40] = (unsigned short(*)[40])smemf;
  unsigned short (*Bs)[40] = (unsigned short(*)[40])((char*)smemf + 10240);
  float (*Sc)[132] = (float(*)[132])smemf;  // 32 x 132 x 4 B = 16896 B
  const int tid = threadIdx.x;
  const int bh = blockIdx.z, b = bh >> 2, h = bh & 3;
  const int m0 = blockIdx.y * 128, n0 = blockIdx.x * 128;
  f32x4 acc[4][4] = {};
  mfma_tile128_bt(xbf + (size_t)b * TT * DD + (size_t)m0 * DD, DD,
                  encT + (size_t)h * NN * DD + (size_t)n0 * DD, DD, DD, acc, As, Bs);
  const int lane = tid & 63, wave = tid >> 6;
  const int fm = lane & 15, fq = lane >> 4;
  const int cw = (wave & 1) << 6;
  const int rbase = ((wave >> 1) << 4) + (fq << 2);
  const size_t base = (size_t)bh * TT * NN;
  const int rr = tid >> 3, cc = (tid & 7) << 4;
  #pragma unroll
  for (int mi = 0; mi < 4; ++mi) {
    __syncthreads();
    #pragma unroll
    for (int ni = 0; ni < 4; ++ni)
      #pragma unroll
      for (int r = 0; r < 4; ++r)
        Sc[rbase + r][cw + ni * 16 + fm] = acc[mi][ni][r];
    __syncthreads();
    float v[16];
    *(float4*)&v[0]  = *(const float4*)&Sc[rr][cc];
    *(float4*)&v[4]  = *(const float4*)&Sc[rr][cc + 4];
    *(float4*)&v[8]  = *(const float4*)&Sc[rr][cc + 8];
    *(float4*)&v[12] = *(const float4*)&Sc[rr][cc + 12];
    const int t = m0 + ((rr >> 4) << 6) + mi * 16 + (rr & 15);
    const int n = n0 + cc;
    #pragma unroll
    for (int j = 0; j < 16; ++j) v[j] = fmaxf(v[j], 0.0f);
    us8 o0, o1;
    #pragma unroll
    for (int j = 0; j < 8; ++j) { o0[j] = f2bf(v[j]); o1[j] = f2bf(v[8 + j]); }
    size_t off = base + (size_t)t * NN + n;
    *(us8*)(xsp + off) = o0;
    *(us8*)(xsp + off + 8) = o1;
    // rope: 8 pairs, thread-local
    float cv[16];
    const float* cp = (const float*)(cs + (size_t)t * NPAIR + (n >> 1));
    *(float4*)&cv[0]  = *(const float4*)(cp);
    *(float4*)&cv[4]  = *(const float4*)(cp + 4);
    *(float4*)&cv[8]  = *(const float4*)(cp + 8);
    *(float4*)&cv[12] = *(const float4*)(cp + 12);
    us8 q0, q1;
    #pragma unroll
    for (int j = 0; j < 8; ++j) {
      float c = cv[2 * j], s = cv[2 * j + 1];
      float ve = v[2 * j], vo = v[2 * j + 1];
      float qe = ve * c - vo * s;
      float qo = vo * c + ve * s;
      if (j < 4) { q0[2 * j] = f2bf(qe); q0[2 * j + 1] = f2bf(qo); }
      else       { q1[2 * (j - 4)] = f2bf(qe); q1[2 * (j - 4) + 1] = f2bf(qo); }
    }
    *(us8*)(qr + off) = q0;
    *(us8*)(qr + off + 8) = q1;
  }
}

// scores partials: scp[bh*4+kc] = qr[:,kc*1024:+1024] · qr^T chunk (f32)
__global__ __launch_bounds__(256) void k_scores_part(const unsigned short* __restrict__ qr,
                                                     float* __restrict__ scp) {
  __shared__ float smemf[5120];
  unsigned short (*As)[40] = (unsigned short(*)[40])smemf;
  unsigned short (*Bs)[40] = (unsigned short(*)[40])((char*)smemf + 10240);
  const int z = blockIdx.z, bh = z >> 2, kc = z & 3;
  const int m0 = blockIdx.y * 128, n0 = blockIdx.x * 128;
  if (n0 > m0) return;  // masked region handled in k_ykv staging
  const unsigned short* Q = qr + (size_t)bh * TT * NN + kc * 1024;
  f32x4 acc[4][4] = {};
  mfma_tile128_bt(Q + (size_t)m0 * NN, NN, Q + (size_t)n0 * NN, NN, 1024, acc, As, Bs);
  const int lane = threadIdx.x & 63, wave = threadIdx.x >> 6;
  const int fm = lane & 15, fq = lane >> 4;
  const int rw = (wave >> 1) << 6, cw = (wave & 1) << 6;
  float* C = scp + (size_t)z * TT * TT;
  #pragma unroll
  for (int ni = 0; ni < 4; ++ni) {
    int s = n0 + cw + ni * 16 + fm;
    #pragma unroll
    for (int mi = 0; mi < 4; ++mi) {
      int trow = m0 + rw + mi * 16 + (fq << 2);
      #pragma unroll
      for (int r = 0; r < 4; ++r)
        C[(size_t)(trow + r) * TT + s] = acc[mi][ni][r];
    }
  }
}

// ykv = (masked sum of scp partials) @ x — 64-tile, scred fused into staging
__global__ __launch_bounds__(256) void k_ykv(const float* __restrict__ scp,
                                             const unsigned short* __restrict__ xTbf,
                                             float* __restrict__ ykv) {
  __shared__ unsigned short As[64][40], Bs[64][40];
  const int tid = threadIdx.x;
  const int bh = blockIdx.z, b = bh >> 2;
  const int m0 = blockIdx.y * 64, n0 = blockIdx.x * 64;
  const int lane = tid & 63, wave = tid >> 6;
  const int srow = tid >> 2, sk = (tid & 3) << 3;
  const int fm = lane & 15, fq = lane >> 4;
  const int t = m0 + srow;  // A row (query index)
  const size_t abase0 = (size_t)(bh * 4) * TT * TT + (size_t)t * TT;
  const unsigned short* Brow = xTbf + ((size_t)b * DD + n0 + srow) * TT;
  f32x4 acc[4] = {};
  for (int k0 = 0; k0 < TT; k0 += 32) {
    us8 bv = *(const us8*)(Brow + k0 + sk);
    us8 av;
    const int s0 = k0 + sk;
    if (s0 >= t) {
      #pragma unroll
      for (int j = 0; j < 8; ++j) av[j] = 0;
    } else {
      const float* p = scp + abase0 + s0;
      float sum[8];
      #pragma unroll
      for (int j = 0; j < 8; ++j) sum[j] = 0.0f;
      #pragma unroll
      for (int kc = 0; kc < 4; ++kc) {
        float4 u0 = *(const float4*)(p + (size_t)kc * TT * TT);
        float4 u1 = *(const float4*)(p + (size_t)kc * TT * TT + 4);
        sum[0] += u0.x; sum[1] += u0.y; sum[2] += u0.z; sum[3] += u0.w;
        sum[4] += u1.x; sum[5] += u1.y; sum[6] += u1.z; sum[7] += u1.w;
      }
      #pragma unroll
      for (int j = 0; j < 8; ++j)
        av[j] = f2bf((s0 + j < t) ? sum[j] : 0.0f);
    }
    __syncthreads();
    *(us8*)(&As[srow][sk]) = av;
    *(us8*)(&Bs[srow][sk]) = bv;
    __syncthreads();
    bf16x8 a = *(const bf16x8*)(&As[wave * 16 + fm][fq << 3]);
    #pragma unroll
    for (int nt = 0; nt < 4; ++nt) {
      bf16x8 bfr = *(const bf16x8*)(&Bs[nt * 16 + fm][fq << 3]);
      acc[nt] = __builtin_amdgcn_mfma_f32_16x16x32_bf16(a, bfr, acc[nt], 0, 0, 0);
    }
  }
  __syncthreads();
  const int trow = m0 + wave * 16 + (fq << 2);
  float* C = ykv + (size_t)bh * TT * DD;
  #pragma unroll
  for (int nt = 0; nt < 4; ++nt) {
    int d = n0 + nt * 16 + fm;
    #pragma unroll
    for (int r = 0; r < 4; ++r)
      C[(size_t)(trow + r) * DD + d] = acc[nt][r];
  }
}

__global__ __launch_bounds__(256) void k_ln_rows(float* __restrict__ p,
                                                 unsigned short* __restrict__ pbf) {
  int row = blockIdx.x, tid = threadIdx.x;
  float v = p[(size_t)row * DD + tid];
  float mu = block_sum_256(v) * (1.0f / DD);
  float d = v - mu;
  float var = block_sum_256(d * d) * (1.0f / DD);
  float r = d * rsqrtf(var + 1e-5f);
  p[(size_t)row * DD + tid] = r;
  pbf[(size_t)row * DD + tid] = f2bf(r);
}

// xy_bf = xsp_bf * relu(ykv_bf @ encv[h]) — LDS-transposed epilogue
__global__ __launch_bounds__(256) void k_ysp_xy(const unsigned short* __restrict__ ykvbf,
                                                const unsigned short* __restrict__ encvT,
                                                const unsigned short* __restrict__ xsp,
                                                unsigned short* __restrict__ xy) {
  __shared__ float smemf[5120];
  unsigned short (*As)[40] = (unsigned short(*)[40])smemf;
  unsigned short (*Bs)[40] = (unsigned short(*)[40])((char*)smemf + 10240);
  float (*Sc)[132] = (float(*)[132])smemf;
  const int tid = threadIdx.x;
  const int bh = blockIdx.z, h = bh & 3;
  const int m0 = blockIdx.y * 128, n0 = blockIdx.x * 128;
  f32x4 acc[4][4] = {};
  mfma_tile128_bt(ykvbf + (size_t)bh * TT * DD + (size_t)m0 * DD, DD,
                  encvT + (size_t)h * NN * DD + (size_t)n0 * DD, DD, DD, acc, As, Bs);
  const int lane = tid & 63, wave = tid >> 6;
  const int fm = lane & 15, fq = lane >> 4;
  const int cw = (wave & 1) << 6;
  const int rbase = ((wave >> 1) << 4) + (fq << 2);
  const size_t base = (size_t)bh * TT * NN;
  const int rr = tid >> 3, cc = (tid & 7) << 4;
  #pragma unroll
  for (int mi = 0; mi < 4; ++mi) {
    __syncthreads();
    #pragma unroll
    for (int ni = 0; ni < 4; ++ni)
      #pragma unroll
      for (int r = 0; r < 4; ++r)
        Sc[rbase + r][cw + ni * 16 + fm] = acc[mi][ni][r];
    __syncthreads();
    float v[16];
    *(float4*)&v[0]  = *(const float4*)&Sc[rr][cc];
    *(float4*)&v[4]  = *(const float4*)&Sc[rr][cc + 4];
    *(float4*)&v[8]  = *(const float4*)&Sc[rr][cc + 8];
    *(float4*)&v[12] = *(const float4*)&Sc[rr][cc + 12];
    const int t = m0 + ((rr >> 4) << 6) + mi * 16 + (rr & 15);
    const int n = n0 + cc;
    size_t off = base + (size_t)t * NN + n;
    us8 x0 = *(const us8*)(xsp + off);
    us8 x1 = *(const us8*)(xsp + off + 8);
    us8 o0, o1;
    #pragma unroll
    for (int j = 0; j < 8; ++j) {
      o0[j] = f2bf(bf2f(x0[j]) * fmaxf(v[j], 0.0f));
      o1[j] = f2bf(bf2f(x1[j]) * fmaxf(v[8 + j], 0.0f));
    }
    *(us8*)(xy + off) = o0;
    *(us8*)(xy + off + 8) = o1;
  }
}

// ym8[bh*2+ks] = xy_bf chunk @ dec[h] chunk  (K-split 2)
__global__ __launch_bounds__(256) void k_ymlp(const unsigned short* __restrict__ xy,
                                              const unsigned short* __restrict__ decT,
                                              float* __restrict__ ym8) {
  __shared__ float smemf[5120];
  unsigned short (*As)[40] = (unsigned short(*)[40])smemf;
  unsigned short (*Bs)[40] = (unsigned short(*)[40])((char*)smemf + 10240);
  const int z = blockIdx.z, bh = z >> 1, ks = z & 1, h = bh & 3;
  const int m0 = blockIdx.y * 128, n0 = blockIdx.x * 128;
  f32x4 acc[4][4] = {};
  mfma_tile128_bt(xy + (size_t)bh * TT * NN + (size_t)m0 * NN + ks * 2048, NN,
                  decT + (size_t)h * DD * NN + (size_t)n0 * NN + ks * 2048, NN,
                  2048, acc, As, Bs);
  const int lane = threadIdx.x & 63, wave = threadIdx.x >> 6;
  const int fm = lane & 15, fq = lane >> 4;
  const int rw = (wave >> 1) << 6, cw = (wave & 1) << 6;
  float* C = ym8 + (size_t)z * TT * DD;
  #pragma unroll
  for (int ni = 0; ni < 4; ++ni) {
    int d = n0 + cw + ni * 16 + fm;
    #pragma unroll
    for (int mi = 0; mi < 4; ++mi) {
      int trow = m0 + rw + mi * 16 + (fq << 2);
      #pragma unroll
      for (int r = 0; r < 4; ++r)
        C[(size_t)(trow + r) * DD + d] = acc[mi][ni][r];
    }
  }
}

// x = LN(x + LN(sum of 8 partials)); emits f32 x, bf16 xbf, bf16 xT
__global__ __launch_bounds__(256) void k_ln2(float* __restrict__ x,
                                             const float* __restrict__ ym8,
                                             unsigned short* __restrict__ xbf,
                                             unsigned short* __restrict__ xTbf) {
  int row = blockIdx.x, tid = threadIdx.x;
  int b = row >> 9, t = row & 511;
  float y = 0.0f;
  #pragma unroll
  for (int p = 0; p < 8; ++p)
    y += ym8[(size_t)(b * 8 + p) * TT * DD + (size_t)t * DD + tid];
  float mu = block_sum_256(y) * (1.0f / DD);
  float d = y - mu;
  float var = block_sum_256(d * d) * (1.0f / DD);
  float ly = d * rsqrtf(var + 1e-5f);
  float xv = x[(size_t)row * DD + tid] + ly;
  float mu2 = block_sum_256(xv) * (1.0f / DD);
  float d2 = xv - mu2;
  float var2 = block_sum_256(d2 * d2) * (1.0f / DD);
  float r = d2 * rsqrtf(var2 + 1e-5f);
  x[(size_t)row * DD + tid] = r;
  unsigned short rb = f2bf(r);
  xbf[(size_t)row * DD + tid] = rb;
  xTbf[((size_t)b * DD + tid) * TT + t] = rb;
}

__global__ __launch_bounds__(256) void k_trace(const unsigned short* __restrict__ xy,
                                               float* __restrict__ out) {
  int idx = blockIdx.x * 256 + threadIdx.x;
  int b = idx >> 14, c = idx & 16383;
  int h = c >> 12, n = c & 4095;
  size_t base = (size_t)(b * 4 + h) * TT * NN + n;
  float s = 0.0f;
  for (int t = 0; t < TT; ++t) s += bf2f(xy[base + (size_t)t * NN]);
  out[idx] = s * (1.0f / TT);
}

__global__ __launch_bounds__(256) void k_logits(const float* __restrict__ x,
                                                const float* __restrict__ W,
                                                float* __restrict__ out) {
  __shared__ float xs[DD];
  int row = blockIdx.x, tid = threadIdx.x;
  xs[tid] = x[(size_t)row * DD + tid];
  __syncthreads();
  float s = 0.0f;
  #pragma unroll 8
  for (int d = 0; d < DD; ++d) s = fmaf(xs[d], W[(size_t)d * VV + tid], s);
  out[(size_t)row * VV + tid] = s;
}

__global__ __launch_bounds__(256) void k_embedding(const float* __restrict__ x,
                                                   float* __restrict__ out) {
  int idx = blockIdx.x * 256 + threadIdx.x;
  int b = idx >> 8, d = idx & 255;
  float s = 0.0f;
  for (int t = 0; t < TT; ++t) s += x[(size_t)(b * TT + t) * DD + d];
  out[idx] = s * (1.0f / TT);
}

extern "C" void kernel_launch(void* const* d_in, const int* in_sizes, int n_in,
                              void* d_out, int out_size, void* d_ws, size_t ws_size,
                              hipStream_t stream) {
  const int*   ids  = (const int*)d_in[0];
  const float* tbl  = (const float*)d_in[1];
  const float* enc  = (const float*)d_in[2];
  const float* encv = (const float*)d_in[3];
  const float* dec  = (const float*)d_in[4];
  const float* lmh  = (const float*)d_in[5];

  // workspace layout (float units), ~155 MiB total
  float* ws   = (float*)d_ws;
  float* x    = ws;                                              //   262,144 f
  unsigned short* scbf  = (unsigned short*)(x + 262144);         // (hole, unused)
  float* ykv  = (float*)(scbf + 2097152);                        // 1,048,576 f
  unsigned short* ykvbf = (unsigned short*)(ykv + 1048576);      // 1,048,576 us
  float* ym8  = (float*)(ykvbf + 1048576);                       // 2,097,152 f
  unsigned short* xbf   = (unsigned short*)(ym8 + 2097152);      //   262,144 us
  unsigned short* xTbf  = xbf + 262144;                          //   262,144 us
  unsigned short* encT  = xTbf + 262144;                         // 4,194,304 us
  unsigned short* encvT = encT + 4194304;                        // 4,194,304 us
  unsigned short* decT  = encvT + 4194304;                       // 4,194,304 us
  unsigned short* xspbf = decT + 4194304;                        // 16,777,216 us
  unsigned short* qxybf = xspbf + 16777216;                      // 16,777,216 us
  float2* cs  = (float2*)(qxybf + 16777216);                     // 1,048,576 float2
  float* scp  = (float*)(cs + 1048576);                          // 8,388,608 f (32 MiB)

  float* out_logits = (float*)d_out;
  float* out_embed  = out_logits + (size_t)BB * TT * VV;
  float* out_trace  = out_embed + (size_t)BB * DD;

  k_csinit<<<(TT * NPAIR) / 256, 256, 0, stream>>>(cs);
  k_tcast<<<dim3(NN / 64, DD / 64, NH), 256, 0, stream>>>(enc,  encT,  DD, NN);
  k_tcast<<<dim3(NN / 64, DD / 64, NH), 256, 0, stream>>>(encv, encvT, DD, NN);
  k_tcast<<<dim3(DD / 64, NN / 64, NH), 256, 0, stream>>>(dec,  decT,  NN, DD);

  k_embed_ln<<<BB * TT, 256, 0, stream>>>(ids, tbl, x, xbf, xTbf);
  for (int l = 0; l < NLAYER; ++l) {
    k_enc        <<<dim3(NN / 128, TT / 128, BH), 256, 0, stream>>>(xbf, encT, cs, xspbf, qxybf);
    k_scores_part<<<dim3(TT / 128, TT / 128, BH * 4), 256, 0, stream>>>(qxybf, scp);
    k_ykv        <<<dim3(DD / 64, TT / 64, BH), 256, 0, stream>>>(scp, xTbf, ykv);
    k_ln_rows    <<<BH * TT, 256, 0, stream>>>(ykv, ykvbf);
    k_ysp_xy     <<<dim3(NN / 128, TT / 128, BH), 256, 0, stream>>>(ykvbf, encvT, xspbf, qxybf);
    k_ymlp       <<<dim3(DD / 128, TT / 128, BH * 2), 256, 0, stream>>>(qxybf, decT, ym8);
    k_ln2        <<<BB * TT, 256, 0, stream>>>(x, ym8, xbf, xTbf);
  }
  k_trace    <<<(BB * NH * NN) / 256, 256, 0, stream>>>(qxybf, out_trace);
  k_logits   <<<BB * TT, 256, 0, stream>>>(x, lmh, out_logits);
  k_embedding<<<(BB * DD) / 256, 256, 0, stream>>>(x, out_embed);
}

// Round 12
// 1009.144 us; speedup vs baseline: 5.9846x; 1.0716x over previous
//
#include <hip/hip_runtime.h>
#include <hip/hip_bf16.h>

#define TT 512
#define DD 256
#define NH 4
#define NN 4096
#define VV 256
#define NLAYER 6
#define BB 2
#define BH (BB * NH)
#define NPAIR 2048

typedef __attribute__((ext_vector_type(8))) short bf16x8;
typedef __attribute__((ext_vector_type(4))) float f32x4;
typedef __attribute__((ext_vector_type(8))) unsigned short us8;

__device__ __forceinline__ unsigned short f2bf(float f) {
  unsigned int u = __float_as_uint(f);
  return (unsigned short)((u + 0x7FFFu + ((u >> 16) & 1u)) >> 16);
}
__device__ __forceinline__ float bf2f(unsigned short h) {
  return __uint_as_float((unsigned int)h << 16);
}

// ---------------- block-wide sum over 256 threads ----------------
__device__ __forceinline__ float block_sum_256(float v) {
  __shared__ float s[4];
  #pragma unroll
  for (int o = 32; o > 0; o >>= 1) v += __shfl_down(v, o);
  int lane = threadIdx.x & 63, wid = threadIdx.x >> 6;
  if (lane == 0) s[wid] = v;
  __syncthreads();
  float r = s[0] + s[1] + s[2] + s[3];
  __syncthreads();
  return r;
}

// ---- 128x128 MFMA tile main loop (verified R9-R11) ----
__device__ __forceinline__ void mfma_tile128_bt(const unsigned short* __restrict__ A, int lda,
                                                const unsigned short* __restrict__ B, int ldb,
                                                int K, f32x4 acc[4][4],
                                                unsigned short (*As)[40],
                                                unsigned short (*Bs)[40]) {
  const int tid = threadIdx.x;
  const int lane = tid & 63, wave = tid >> 6;
  const int fm = lane & 15, fq = lane >> 4;
  const int rw = (wave >> 1) << 6, cw = (wave & 1) << 6;
  const int r0s = tid >> 2, c0s = (tid & 3) << 3;
  for (int k0 = 0; k0 < K; k0 += 32) {
    us8 a0 = *(const us8*)(A + (size_t)r0s * lda + k0 + c0s);
    us8 a1 = *(const us8*)(A + (size_t)(r0s + 64) * lda + k0 + c0s);
    us8 b0 = *(const us8*)(B + (size_t)r0s * ldb + k0 + c0s);
    us8 b1 = *(const us8*)(B + (size_t)(r0s + 64) * ldb + k0 + c0s);
    __syncthreads();
    *(us8*)(&As[r0s][c0s]) = a0;
    *(us8*)(&As[r0s + 64][c0s]) = a1;
    *(us8*)(&Bs[r0s][c0s]) = b0;
    *(us8*)(&Bs[r0s + 64][c0s]) = b1;
    __syncthreads();
    bf16x8 af[4], bfv[4];
    #pragma unroll
    for (int i = 0; i < 4; ++i) {
      af[i]  = *(const bf16x8*)(&As[rw + i * 16 + fm][fq << 3]);
      bfv[i] = *(const bf16x8*)(&Bs[cw + i * 16 + fm][fq << 3]);
    }
    #pragma unroll
    for (int mi = 0; mi < 4; ++mi)
      #pragma unroll
      for (int ni = 0; ni < 4; ++ni)
        acc[mi][ni] = __builtin_amdgcn_mfma_f32_16x16x32_bf16(af[mi], bfv[ni], acc[mi][ni], 0, 0, 0);
  }
}
// C/D: row = m0 + rw + mi*16 + (lane>>4)*4 + r ; col = n0 + cw + ni*16 + (lane&15)

// ---------------- small kernels ----------------

__global__ __launch_bounds__(256) void k_csinit(float2* __restrict__ cs) {
  int idx = blockIdx.x * 256 + threadIdx.x;
  int t = idx >> 11, p = idx & (NPAIR - 1);
  const float INV2PI = 0.15915494309189535f;
  const float TWOPI = 6.283185307179586f;
  float f = exp2f(-16.0f * (float)(2 * p) / (float)NN) * INV2PI;
  float ph = fmodf((float)t * f, 1.0f) * TWOPI;
  float s, c;
  sincosf(ph, &s, &c);
  cs[idx] = make_float2(c, s);
}

__global__ __launch_bounds__(256) void k_tcast(const float* __restrict__ in,
                                               unsigned short* __restrict__ out,
                                               int R, int C) {
  __shared__ float tile[64][65];
  const size_t zoff = (size_t)blockIdx.z * R * C;
  const int r0 = blockIdx.y * 64, c0 = blockIdx.x * 64;
  const int cl = threadIdx.x & 63, r4 = threadIdx.x >> 6;
  #pragma unroll 4
  for (int i = 0; i < 16; ++i) {
    int rl = r4 * 16 + i;
    tile[rl][cl] = in[zoff + (size_t)(r0 + rl) * C + c0 + cl];
  }
  __syncthreads();
  #pragma unroll 4
  for (int i = 0; i < 16; ++i) {
    int ccl = r4 * 16 + i;
    out[zoff + (size_t)(c0 + ccl) * R + r0 + cl] = f2bf(tile[cl][ccl]);
  }
}

// x[b,t,:] = LN(embed[ids]); emits f32 x, bf16 xbf, bf16 xT
__global__ __launch_bounds__(256) void k_embed_ln(const int* __restrict__ idw,
                                                  const float* __restrict__ tbl,
                                                  float* __restrict__ x,
                                                  unsigned short* __restrict__ xbf,
                                                  unsigned short* __restrict__ xTbf) {
  __shared__ int s_id;
  int row = blockIdx.x, tid = threadIdx.x;
  if (tid == 0) {
    bool is64 = true;
    for (int i = 1; i < 64; i += 2)
      if (idw[i] != 0) { is64 = false; break; }
    s_id = is64 ? idw[2 * row] : idw[row];
  }
  __syncthreads();
  int id = s_id;
  float v = tbl[(size_t)id * DD + tid];
  float mu = block_sum_256(v) * (1.0f / DD);
  float d = v - mu;
  float var = block_sum_256(d * d) * (1.0f / DD);
  float r = d * rsqrtf(var + 1e-5f);
  x[(size_t)row * DD + tid] = r;
  unsigned short rb = f2bf(r);
  xbf[(size_t)row * DD + tid] = rb;
  int b = row >> 9, t = row & 511;
  xTbf[((size_t)b * DD + tid) * TT + t] = rb;
}

// ---------------- GEMM kernels ----------------

// xsp = bf16(relu(x @ enc[h])); qr = bf16(rope(relu)) — LDS-transposed epilogue
__global__ __launch_bounds__(256) void k_enc(const unsigned short* __restrict__ xbf,
                                             const unsigned short* __restrict__ encT,
                                             const float2* __restrict__ cs,
                                             unsigned short* __restrict__ xsp,
                                             unsigned short* __restrict__ qr) {
  __shared__ float smemf[5120];
  unsigned short (*As)[40] = (unsigned short(*)[40])smemf;
  unsigned short (*Bs)[40] = (unsigned short(*)[40])((char*)smemf + 10240);
  float (*Sc)[132] = (float(*)[132])smemf;
  const int tid = threadIdx.x;
  const int bh = blockIdx.z, b = bh >> 2, h = bh & 3;
  const int m0 = blockIdx.y * 128, n0 = blockIdx.x * 128;
  f32x4 acc[4][4] = {};
  mfma_tile128_bt(xbf + (size_t)b * TT * DD + (size_t)m0 * DD, DD,
                  encT + (size_t)h * NN * DD + (size_t)n0 * DD, DD, DD, acc, As, Bs);
  const int lane = tid & 63, wave = tid >> 6;
  const int fm = lane & 15, fq = lane >> 4;
  const int cw = (wave & 1) << 6;
  const int rbase = ((wave >> 1) << 4) + (fq << 2);
  const size_t base = (size_t)bh * TT * NN;
  const int rr = tid >> 3, cc = (tid & 7) << 4;
  #pragma unroll
  for (int mi = 0; mi < 4; ++mi) {
    __syncthreads();
    #pragma unroll
    for (int ni = 0; ni < 4; ++ni)
      #pragma unroll
      for (int r = 0; r < 4; ++r)
        Sc[rbase + r][cw + ni * 16 + fm] = acc[mi][ni][r];
    __syncthreads();
    float v[16];
    *(float4*)&v[0]  = *(const float4*)&Sc[rr][cc];
    *(float4*)&v[4]  = *(const float4*)&Sc[rr][cc + 4];
    *(float4*)&v[8]  = *(const float4*)&Sc[rr][cc + 8];
    *(float4*)&v[12] = *(const float4*)&Sc[rr][cc + 12];
    const int t = m0 + ((rr >> 4) << 6) + mi * 16 + (rr & 15);
    const int n = n0 + cc;
    #pragma unroll
    for (int j = 0; j < 16; ++j) v[j] = fmaxf(v[j], 0.0f);
    us8 o0, o1;
    #pragma unroll
    for (int j = 0; j < 8; ++j) { o0[j] = f2bf(v[j]); o1[j] = f2bf(v[8 + j]); }
    size_t off = base + (size_t)t * NN + n;
    *(us8*)(xsp + off) = o0;
    *(us8*)(xsp + off + 8) = o1;
    float cv[16];
    const float* cp = (const float*)(cs + (size_t)t * NPAIR + (n >> 1));
    *(float4*)&cv[0]  = *(const float4*)(cp);
    *(float4*)&cv[4]  = *(const float4*)(cp + 4);
    *(float4*)&cv[8]  = *(const float4*)(cp + 8);
    *(float4*)&cv[12] = *(const float4*)(cp + 12);
    us8 q0, q1;
    #pragma unroll
    for (int j = 0; j < 8; ++j) {
      float c = cv[2 * j], s = cv[2 * j + 1];
      float ve = v[2 * j], vo = v[2 * j + 1];
      float qe = ve * c - vo * s;
      float qo = vo * c + ve * s;
      if (j < 4) { q0[2 * j] = f2bf(qe); q0[2 * j + 1] = f2bf(qo); }
      else       { q1[2 * (j - 4)] = f2bf(qe); q1[2 * (j - 4) + 1] = f2bf(qo); }
    }
    *(us8*)(qr + off) = q0;
    *(us8*)(qr + off + 8) = q1;
  }
}

// scores partials: scp[bh*4+kc] = qr[:,kc*1024:+1024] · qr^T chunk (f32)
__global__ __launch_bounds__(256) void k_scores_part(const unsigned short* __restrict__ qr,
                                                     float* __restrict__ scp) {
  __shared__ float smemf[5120];
  unsigned short (*As)[40] = (unsigned short(*)[40])smemf;
  unsigned short (*Bs)[40] = (unsigned short(*)[40])((char*)smemf + 10240);
  const int z = blockIdx.z, bh = z >> 2, kc = z & 3;
  const int m0 = blockIdx.y * 128, n0 = blockIdx.x * 128;
  if (n0 > m0) return;  // masked region handled in k_ykv_ln staging
  const unsigned short* Q = qr + (size_t)bh * TT * NN + kc * 1024;
  f32x4 acc[4][4] = {};
  mfma_tile128_bt(Q + (size_t)m0 * NN, NN, Q + (size_t)n0 * NN, NN, 1024, acc, As, Bs);
  const int lane = threadIdx.x & 63, wave = threadIdx.x >> 6;
  const int fm = lane & 15, fq = lane >> 4;
  const int rw = (wave >> 1) << 6, cw = (wave & 1) << 6;
  float* C = scp + (size_t)z * TT * TT;
  #pragma unroll
  for (int ni = 0; ni < 4; ++ni) {
    int s = n0 + cw + ni * 16 + fm;
    #pragma unroll
    for (int mi = 0; mi < 4; ++mi) {
      int trow = m0 + rw + mi * 16 + (fq << 2);
      #pragma unroll
      for (int r = 0; r < 4; ++r)
        C[(size_t)(trow + r) * TT + s] = acc[mi][ni][r];
    }
  }
}

// ykvbf = bf16(LN((masked sum of scp) @ x)) — 64x256 wide tile, LN fused
// wave w: rows w*16..w*16+16 of the 64-row tile, all 256 cols (16 accs).
__global__ __launch_bounds__(256) void k_ykv_ln(const float* __restrict__ scp,
                                                const unsigned short* __restrict__ xTbf,
                                                unsigned short* __restrict__ ykvbf) {
  __shared__ unsigned short As[64][40];   // 5120 B
  __shared__ unsigned short Bs[256][40];  // 20480 B
  const int tid = threadIdx.x;
  const int m0 = blockIdx.x * 64, bh = blockIdx.y, b = bh >> 2;
  const int lane = tid & 63, wave = tid >> 6;
  const int srow = tid >> 2, sk = (tid & 3) << 3;
  const int fm = lane & 15, fq = lane >> 4;
  const int t = m0 + srow;
  const size_t abase0 = (size_t)(bh * 4) * TT * TT + (size_t)t * TT;
  const unsigned short* Brow = xTbf + ((size_t)b * DD + tid) * TT;
  f32x4 acc[16] = {};
  for (int k0 = 0; k0 < TT; k0 += 32) {
    // A: fused scred (sum 4 partials) + strict-lower mask
    us8 av;
    const int s0 = k0 + sk;
    if (s0 >= t) {
      #pragma unroll
      for (int j = 0; j < 8; ++j) av[j] = 0;
    } else {
      const float* p = scp + abase0 + s0;
      float sum[8];
      #pragma unroll
      for (int j = 0; j < 8; ++j) sum[j] = 0.0f;
      #pragma unroll
      for (int kc = 0; kc < 4; ++kc) {
        float4 u0 = *(const float4*)(p + (size_t)kc * TT * TT);
        float4 u1 = *(const float4*)(p + (size_t)kc * TT * TT + 4);
        sum[0] += u0.x; sum[1] += u0.y; sum[2] += u0.z; sum[3] += u0.w;
        sum[4] += u1.x; sum[5] += u1.y; sum[6] += u1.z; sum[7] += u1.w;
      }
      #pragma unroll
      for (int j = 0; j < 8; ++j)
        av[j] = f2bf((s0 + j < t) ? sum[j] : 0.0f);
    }
    us8 bv0 = *(const us8*)(Brow + k0);
    us8 bv1 = *(const us8*)(Brow + k0 + 8);
    us8 bv2 = *(const us8*)(Brow + k0 + 16);
    us8 bv3 = *(const us8*)(Brow + k0 + 24);
    __syncthreads();
    *(us8*)(&As[srow][sk]) = av;
    *(us8*)(&Bs[tid][0]) = bv0;
    *(us8*)(&Bs[tid][8]) = bv1;
    *(us8*)(&Bs[tid][16]) = bv2;
    *(us8*)(&Bs[tid][24]) = bv3;
    __syncthreads();
    bf16x8 a = *(const bf16x8*)(&As[wave * 16 + fm][fq << 3]);
    #pragma unroll
    for (int ni = 0; ni < 16; ++ni) {
      bf16x8 bfr = *(const bf16x8*)(&Bs[ni * 16 + fm][fq << 3]);
      acc[ni] = __builtin_amdgcn_mfma_f32_16x16x32_bf16(a, bfr, acc[ni], 0, 0, 0);
    }
  }
  // fused LN over the 256-wide rows (reduce across the 16-lane fm group)
  float p1[4], p2[4];
  #pragma unroll
  for (int r = 0; r < 4; ++r) { p1[r] = 0.0f; p2[r] = 0.0f; }
  #pragma unroll
  for (int ni = 0; ni < 16; ++ni)
    #pragma unroll
    for (int r = 0; r < 4; ++r) {
      float v = acc[ni][r];
      p1[r] += v; p2[r] += v * v;
    }
  #pragma unroll
  for (int off = 1; off < 16; off <<= 1)
    #pragma unroll
    for (int r = 0; r < 4; ++r) {
      p1[r] += __shfl_xor(p1[r], off);
      p2[r] += __shfl_xor(p2[r], off);
    }
  const int trow = m0 + wave * 16 + (fq << 2);
  #pragma unroll
  for (int r = 0; r < 4; ++r) {
    float mu = p1[r] * (1.0f / DD);
    float var = p2[r] * (1.0f / DD) - mu * mu;
    float sc = rsqrtf(var + 1e-5f);
    unsigned short* C = ykvbf + ((size_t)bh * TT + trow + r) * DD;
    #pragma unroll
    for (int ni = 0; ni < 16; ++ni)
      C[ni * 16 + fm] = f2bf((acc[ni][r] - mu) * sc);
  }
}

// xy_bf = xsp_bf * relu(ykv_bf @ encv[h]) — LDS-transposed epilogue
__global__ __launch_bounds__(256) void k_ysp_xy(const unsigned short* __restrict__ ykvbf,
                                                const unsigned short* __restrict__ encvT,
                                                const unsigned short* __restrict__ xsp,
                                                unsigned short* __restrict__ xy) {
  __shared__ float smemf[5120];
  unsigned short (*As)[40] = (unsigned short(*)[40])smemf;
  unsigned short (*Bs)[40] = (unsigned short(*)[40])((char*)smemf + 10240);
  float (*Sc)[132] = (float(*)[132])smemf;
  const int tid = threadIdx.x;
  const int bh = blockIdx.z, h = bh & 3;
  const int m0 = blockIdx.y * 128, n0 = blockIdx.x * 128;
  f32x4 acc[4][4] = {};
  mfma_tile128_bt(ykvbf + (size_t)bh * TT * DD + (size_t)m0 * DD, DD,
                  encvT + (size_t)h * NN * DD + (size_t)n0 * DD, DD, DD, acc, As, Bs);
  const int lane = tid & 63, wave = tid >> 6;
  const int fm = lane & 15, fq = lane >> 4;
  const int cw = (wave & 1) << 6;
  const int rbase = ((wave >> 1) << 4) + (fq << 2);
  const size_t base = (size_t)bh * TT * NN;
  const int rr = tid >> 3, cc = (tid & 7) << 4;
  #pragma unroll
  for (int mi = 0; mi < 4; ++mi) {
    __syncthreads();
    #pragma unroll
    for (int ni = 0; ni < 4; ++ni)
      #pragma unroll
      for (int r = 0; r < 4; ++r)
        Sc[rbase + r][cw + ni * 16 + fm] = acc[mi][ni][r];
    __syncthreads();
    float v[16];
    *(float4*)&v[0]  = *(const float4*)&Sc[rr][cc];
    *(float4*)&v[4]  = *(const float4*)&Sc[rr][cc + 4];
    *(float4*)&v[8]  = *(const float4*)&Sc[rr][cc + 8];
    *(float4*)&v[12] = *(const float4*)&Sc[rr][cc + 12];
    const int t = m0 + ((rr >> 4) << 6) + mi * 16 + (rr & 15);
    const int n = n0 + cc;
    size_t off = base + (size_t)t * NN + n;
    us8 x0 = *(const us8*)(xsp + off);
    us8 x1 = *(const us8*)(xsp + off + 8);
    us8 o0, o1;
    #pragma unroll
    for (int j = 0; j < 8; ++j) {
      o0[j] = f2bf(bf2f(x0[j]) * fmaxf(v[j], 0.0f));
      o1[j] = f2bf(bf2f(x1[j]) * fmaxf(v[8 + j], 0.0f));
    }
    *(us8*)(xy + off) = o0;
    *(us8*)(xy + off + 8) = o1;
  }
}

// ym32[bh*8+ks] = xy_bf chunk @ dec[h] chunk  (K-split 8)
__global__ __launch_bounds__(256) void k_ymlp(const unsigned short* __restrict__ xy,
                                              const unsigned short* __restrict__ decT,
                                              float* __restrict__ ym32) {
  __shared__ float smemf[5120];
  unsigned short (*As)[40] = (unsigned short(*)[40])smemf;
  unsigned short (*Bs)[40] = (unsigned short(*)[40])((char*)smemf + 10240);
  const int z = blockIdx.z, bh = z >> 3, ks = z & 7, h = bh & 3;
  const int m0 = blockIdx.y * 128, n0 = blockIdx.x * 128;
  f32x4 acc[4][4] = {};
  mfma_tile128_bt(xy + (size_t)bh * TT * NN + (size_t)m0 * NN + ks * 512, NN,
                  decT + (size_t)h * DD * NN + (size_t)n0 * NN + ks * 512, NN,
                  512, acc, As, Bs);
  const int lane = threadIdx.x & 63, wave = threadIdx.x >> 6;
  const int fm = lane & 15, fq = lane >> 4;
  const int rw = (wave >> 1) << 6, cw = (wave & 1) << 6;
  float* C = ym32 + (size_t)z * TT * DD;
  #pragma unroll
  for (int ni = 0; ni < 4; ++ni) {
    int d = n0 + cw + ni * 16 + fm;
    #pragma unroll
    for (int mi = 0; mi < 4; ++mi) {
      int trow = m0 + rw + mi * 16 + (fq << 2);
      #pragma unroll
      for (int r = 0; r < 4; ++r)
        C[(size_t)(trow + r) * DD + d] = acc[mi][ni][r];
    }
  }
}

// x = LN(x + LN(sum of 32 partials)); emits f32 x, bf16 xbf, bf16 xT
__global__ __launch_bounds__(256) void k_ln2(float* __restrict__ x,
                                             const float* __restrict__ ym32,
                                             unsigned short* __restrict__ xbf,
                                             unsigned short* __restrict__ xTbf) {
  int row = blockIdx.x, tid = threadIdx.x;
  int b = row >> 9, t = row & 511;
  float y = 0.0f;
  for (int p = 0; p < 32; ++p)
    y += ym32[(size_t)(b * 32 + p) * TT * DD + (size_t)t * DD + tid];
  float mu = block_sum_256(y) * (1.0f / DD);
  float d = y - mu;
  float var = block_sum_256(d * d) * (1.0f / DD);
  float ly = d * rsqrtf(var + 1e-5f);
  float xv = x[(size_t)row * DD + tid] + ly;
  float mu2 = block_sum_256(xv) * (1.0f / DD);
  float d2 = xv - mu2;
  float var2 = block_sum_256(d2 * d2) * (1.0f / DD);
  float r = d2 * rsqrtf(var2 + 1e-5f);
  x[(size_t)row * DD + tid] = r;
  unsigned short rb = f2bf(r);
  xbf[(size_t)row * DD + tid] = rb;
  xTbf[((size_t)b * DD + tid) * TT + t] = rb;
}

__global__ __launch_bounds__(256) void k_trace(const unsigned short* __restrict__ xy,
                                               float* __restrict__ out) {
  int idx = blockIdx.x * 256 + threadIdx.x;
  int b = idx >> 14, c = idx & 16383;
  int h = c >> 12, n = c & 4095;
  size_t base = (size_t)(b * 4 + h) * TT * NN + n;
  float s = 0.0f;
  for (int t = 0; t < TT; ++t) s += bf2f(xy[base + (size_t)t * NN]);
  out[idx] = s * (1.0f / TT);
}

__global__ __launch_bounds__(256) void k_logits(const float* __restrict__ x,
                                                const float* __restrict__ W,
                                                float* __restrict__ out) {
  __shared__ float xs[DD];
  int row = blockIdx.x, tid = threadIdx.x;
  xs[tid] = x[(size_t)row * DD + tid];
  __syncthreads();
  float s = 0.0f;
  #pragma unroll 8
  for (int d = 0; d < DD; ++d) s = fmaf(xs[d], W[(size_t)d * VV + tid], s);
  out[(size_t)row * VV + tid] = s;
}

__global__ __launch_bounds__(256) void k_embedding(const float* __restrict__ x,
                                                   float* __restrict__ out) {
  int idx = blockIdx.x * 256 + threadIdx.x;
  int b = idx >> 8, d = idx & 255;
  float s = 0.0f;
  for (int t = 0; t < TT; ++t) s += x[(size_t)(b * TT + t) * DD + d];
  out[idx] = s * (1.0f / TT);
}

extern "C" void kernel_launch(void* const* d_in, const int* in_sizes, int n_in,
                              void* d_out, int out_size, void* d_ws, size_t ws_size,
                              hipStream_t stream) {
  const int*   ids  = (const int*)d_in[0];
  const float* tbl  = (const float*)d_in[1];
  const float* enc  = (const float*)d_in[2];
  const float* encv = (const float*)d_in[3];
  const float* dec  = (const float*)d_in[4];
  const float* lmh  = (const float*)d_in[5];

  // workspace layout (float units), ~164 MiB total
  float* ws   = (float*)d_ws;
  float* x    = ws;                                              //   262,144 f
  unsigned short* ykvbf = (unsigned short*)(x + 262144);         // 1,048,576 us
  float* ym32 = (float*)(ykvbf + 1048576);                       // 8,388,608 f
  unsigned short* xbf   = (unsigned short*)(ym32 + 8388608);     //   262,144 us
  unsigned short* xTbf  = xbf + 262144;                          //   262,144 us
  unsigned short* encT  = xTbf + 262144;                         // 4,194,304 us
  unsigned short* encvT = encT + 4194304;                        // 4,194,304 us
  unsigned short* decT  = encvT + 4194304;                       // 4,194,304 us
  unsigned short* xspbf = decT + 4194304;                        // 16,777,216 us
  unsigned short* qxybf = xspbf + 16777216;                      // 16,777,216 us
  float2* cs  = (float2*)(qxybf + 16777216);                     // 1,048,576 float2
  float* scp  = (float*)(cs + 1048576);                          // 8,388,608 f (32 MiB)

  float* out_logits = (float*)d_out;
  float* out_embed  = out_logits + (size_t)BB * TT * VV;
  float* out_trace  = out_embed + (size_t)BB * DD;

  k_csinit<<<(TT * NPAIR) / 256, 256, 0, stream>>>(cs);
  k_tcast<<<dim3(NN / 64, DD / 64, NH), 256, 0, stream>>>(enc,  encT,  DD, NN);
  k_tcast<<<dim3(NN / 64, DD / 64, NH), 256, 0, stream>>>(encv, encvT, DD, NN);
  k_tcast<<<dim3(DD / 64, NN / 64, NH), 256, 0, stream>>>(dec,  decT,  NN, DD);

  k_embed_ln<<<BB * TT, 256, 0, stream>>>(ids, tbl, x, xbf, xTbf);
  for (int l = 0; l < NLAYER; ++l) {
    k_enc        <<<dim3(NN / 128, TT / 128, BH), 256, 0, stream>>>(xbf, encT, cs, xspbf, qxybf);
    k_scores_part<<<dim3(TT / 128, TT / 128, BH * 4), 256, 0, stream>>>(qxybf, scp);
    k_ykv_ln     <<<dim3(TT / 64, BH), 256, 0, stream>>>(scp, xTbf, ykvbf);
    k_ysp_xy     <<<dim3(NN / 128, TT / 128, BH), 256, 0, stream>>>(ykvbf, encvT, xspbf, qxybf);
    k_ymlp       <<<dim3(DD / 128, TT / 128, BH * 8), 256, 0, stream>>>(qxybf, decT, ym32);
    k_ln2        <<<BB * TT, 256, 0, stream>>>(x, ym32, xbf, xTbf);
  }
  k_trace    <<<(BB * NH * NN) / 256, 256, 0, stream>>>(qxybf, out_trace);
  k_logits   <<<BB * TT, 256, 0, stream>>>(x, lmh, out_logits);
  k_embedding<<<(BB * DD) / 256, 256, 0, stream>>>(x, out_embed);
}